// Round 1
// baseline (2497.469 us; speedup 1.0000x reference)
//
#include <hip/hip_runtime.h>
#include <math.h>

// ---------------- constants ----------------
// levels: (64,64) start 0, (32,32) start 4096, (16,16) start 5120; L=5376, C=256
#define LTOT 5376

static __device__ __forceinline__ float4 ld4(const float* p) { return *(const float4*)p; }

// ---------------- generic tiled fp32 GEMM ----------------
// out[m,n] = sum_k A(m,k) * B(n,k or k,n) + bias
// A_KM:  A is (K x M), m contiguous, lda = row stride (A[k*lda+m]); else A[m*lda+k]
// B_KN:  B is (K x N), n contiguous (B[k*ldb+n]); else B[n*ldb+k]
// BIAS_ROW: bias indexed by m (row), else by n (col)
template<bool A_KM, bool B_KN, bool RELU, bool BIAS_ROW>
__global__ __launch_bounds__(256) void gemm_k(
    const float* __restrict__ A, int lda,
    const float* __restrict__ B, int ldb,
    const float* __restrict__ bias,
    float* __restrict__ Cm, int ldc,
    int M, int N, int K)
{
    __shared__ float As[32][64];
    __shared__ float Bs[32][64];
    const int tid = threadIdx.x;
    const int m0 = blockIdx.y * 64;
    const int n0 = blockIdx.x * 64;
    const int tm = tid >> 4;
    const int tn = tid & 15;
    float acc[4][4] = {};

    for (int k0 = 0; k0 < K; k0 += 32) {
        #pragma unroll
        for (int i = 0; i < 2; i++) {
            int id = tid + i * 256;
            if (A_KM) {
                int k = id >> 4, mq = (id & 15) << 2;
                *(float4*)&As[k][mq] = ld4(&A[(size_t)(k0 + k) * lda + m0 + mq]);
            } else {
                int m = id >> 3, kq = (id & 7) << 2;
                float4 v = ld4(&A[(size_t)(m0 + m) * lda + k0 + kq]);
                As[kq + 0][m] = v.x; As[kq + 1][m] = v.y;
                As[kq + 2][m] = v.z; As[kq + 3][m] = v.w;
            }
        }
        #pragma unroll
        for (int i = 0; i < 2; i++) {
            int id = tid + i * 256;
            if (B_KN) {
                int k = id >> 4, nq = (id & 15) << 2;
                float4 v = make_float4(0.f, 0.f, 0.f, 0.f);
                if (n0 + nq < N) v = ld4(&B[(size_t)(k0 + k) * ldb + n0 + nq]);
                *(float4*)&Bs[k][nq] = v;
            } else {
                int n = id >> 3, kq = (id & 7) << 2;
                float4 v = make_float4(0.f, 0.f, 0.f, 0.f);
                if (n0 + n < N) v = ld4(&B[(size_t)(n0 + n) * ldb + k0 + kq]);
                Bs[kq + 0][n] = v.x; Bs[kq + 1][n] = v.y;
                Bs[kq + 2][n] = v.z; Bs[kq + 3][n] = v.w;
            }
        }
        __syncthreads();
        #pragma unroll
        for (int kk = 0; kk < 32; kk++) {
            float4 a = *(const float4*)&As[kk][tm << 2];
            float4 b = *(const float4*)&Bs[kk][tn << 2];
            float av[4] = {a.x, a.y, a.z, a.w};
            float bv[4] = {b.x, b.y, b.z, b.w};
            #pragma unroll
            for (int i = 0; i < 4; i++)
                #pragma unroll
                for (int j = 0; j < 4; j++)
                    acc[i][j] = fmaf(av[i], bv[j], acc[i][j]);
        }
        __syncthreads();
    }

    int n = n0 + (tn << 2);
    if (n >= N) return;
    float4 cb = make_float4(0.f, 0.f, 0.f, 0.f);
    if (!BIAS_ROW) cb = ld4(&bias[n]);
    #pragma unroll
    for (int i = 0; i < 4; i++) {
        int row = m0 + (tm << 2) + i;
        if (row >= M) continue;
        float rb = BIAS_ROW ? bias[row] : 0.f;
        float4 o;
        o.x = acc[i][0] + cb.x + rb;
        o.y = acc[i][1] + cb.y + rb;
        o.z = acc[i][2] + cb.z + rb;
        o.w = acc[i][3] + cb.w + rb;
        if (RELU) {
            o.x = fmaxf(o.x, 0.f); o.y = fmaxf(o.y, 0.f);
            o.z = fmaxf(o.z, 0.f); o.w = fmaxf(o.w, 0.f);
        }
        *(float4*)&Cm[(size_t)row * ldc + n] = o;
    }
}

// ---------------- sine positional encoding ----------------
__global__ void posenc_k(float* __restrict__ pos)
{
    int idx = blockIdx.x * blockDim.x + threadIdx.x;
    if (idx >= LTOT * 128) return;
    int l = idx >> 7;
    int pr = idx & 127;
    int half = pr >> 6;   // 0 -> y part, 1 -> x part
    int j = pr & 63;
    int HW, sh, p;
    if (l < 4096)      { HW = 64; sh = 6; p = l; }
    else if (l < 5120) { HW = 32; sh = 5; p = l - 4096; }
    else               { HW = 16; sh = 4; p = l - 5120; }
    int y = p >> sh;
    int x = p & (HW - 1);
    float T = powf(10000.f, (float)j * (1.f / 64.f));
    float coord = (half == 0) ? (float)(y + 1) : (float)(x + 1);
    float v = coord / ((float)HW + 1e-6f) * 6.283185307179586f;
    float arg = v / T;
    size_t base = (size_t)l * 256 + half * 128 + (j << 1);
    pos[base]     = sinf(arg);
    pos[base + 1] = cosf(arg);
}

// ---------------- elementwise add (q = src + pos) ----------------
__global__ void add_k(const float* __restrict__ a, const float* __restrict__ b,
                      float* __restrict__ o, int n4)
{
    int i = blockIdx.x * blockDim.x + threadIdx.x;
    if (i >= n4) return;
    float4 x = ld4(&a[(size_t)i << 2]);
    float4 y = ld4(&b[(size_t)i << 2]);
    x.x += y.x; x.y += y.y; x.z += y.z; x.w += y.w;
    *(float4*)&o[(size_t)i << 2] = x;
}

// ---------------- softmax over 12 (per l, head) ----------------
__global__ void softmax12_k(float* __restrict__ aw)
{
    int r = blockIdx.x * blockDim.x + threadIdx.x;
    if (r >= LTOT * 8) return;
    float* p = aw + (size_t)r * 12;
    float mx = -1e30f;
    float v[12];
    #pragma unroll
    for (int j = 0; j < 12; j++) { v[j] = p[j]; mx = fmaxf(mx, v[j]); }
    float s = 0.f;
    #pragma unroll
    for (int j = 0; j < 12; j++) { v[j] = expf(v[j] - mx); s += v[j]; }
    float inv = 1.f / s;
    #pragma unroll
    for (int j = 0; j < 12; j++) p[j] = v[j] * inv;
}

// ---------------- multi-scale deformable attention sampling ----------------
// value: (L, 256) [= (L, 8 heads, 32)]; off: (L, 192); aw: (L, 96); out: (L, 256)
__global__ __launch_bounds__(256) void msdef_k(
    const float* __restrict__ val, const float* __restrict__ off,
    const float* __restrict__ aw, float* __restrict__ out)
{
    const int l = blockIdx.x;
    const int tid = threadIdx.x;
    __shared__ float soff[192];
    __shared__ float saw[96];
    if (tid < 192) soff[tid] = off[(size_t)l * 192 + tid];
    if (tid < 96)  saw[tid]  = aw[(size_t)l * 96 + tid];
    __syncthreads();
    const int h = tid >> 5;

    float rx, ry;
    {
        int HW, sh, p;
        if (l < 4096)      { HW = 64; sh = 6; p = l; }
        else if (l < 5120) { HW = 32; sh = 5; p = l - 4096; }
        else               { HW = 16; sh = 4; p = l - 5120; }
        int y = p >> sh;
        int x = p & (HW - 1);
        rx = (x + 0.5f) / (float)HW;
        ry = (y + 0.5f) / (float)HW;
    }

    const int starts[3] = {0, 4096, 5120};
    const int dims[3]   = {64, 32, 16};
    float acc = 0.f;
    #pragma unroll
    for (int s = 0; s < 3; s++) {
        const int D = dims[s];
        const int st = starts[s];
        #pragma unroll
        for (int pt = 0; pt < 4; pt++) {
            int ob = h * 24 + s * 8 + (pt << 1);
            float a  = saw[h * 12 + (s << 2) + pt];
            float px = rx * D + soff[ob]     - 0.5f;
            float py = ry * D + soff[ob + 1] - 0.5f;
            float x0f = floorf(px), y0f = floorf(py);
            float lx = px - x0f, ly = py - y0f;
            int x0 = (int)x0f, y0 = (int)y0f;
            float w00 = a * (1.f - lx) * (1.f - ly);
            float w10 = a * lx * (1.f - ly);
            float w01 = a * (1.f - lx) * ly;
            float w11 = a * lx * ly;
            #pragma unroll
            for (int cy = 0; cy < 2; cy++) {
                int yi = y0 + cy;
                if (yi < 0 || yi >= D) continue;
                #pragma unroll
                for (int cx = 0; cx < 2; cx++) {
                    int xi = x0 + cx;
                    if (xi < 0 || xi >= D) continue;
                    float w = cy ? (cx ? w11 : w01) : (cx ? w10 : w00);
                    acc += w * val[((size_t)(st + yi * D + xi)) * 256 + tid];
                }
            }
        }
    }
    out[(size_t)l * 256 + tid] = acc;
}

// ---------------- layernorm (optionally with residual add), in-place on src ----------------
template<bool HAS_ADD>
__global__ __launch_bounds__(256) void ln_k(float* __restrict__ src, const float* __restrict__ add,
                                            const float* __restrict__ w, const float* __restrict__ b)
{
    int row = blockIdx.x * 4 + (threadIdx.x >> 6);
    int lane = threadIdx.x & 63;
    size_t base = (size_t)row * 256 + (lane << 2);
    float4 x = ld4(&src[base]);
    if (HAS_ADD) {
        float4 a = ld4(&add[base]);
        x.x += a.x; x.y += a.y; x.z += a.z; x.w += a.w;
    }
    float s = x.x + x.y + x.z + x.w;
    #pragma unroll
    for (int o = 32; o > 0; o >>= 1) s += __shfl_xor(s, o, 64);
    float m = s * (1.f / 256.f);
    float d0 = x.x - m, d1 = x.y - m, d2 = x.z - m, d3 = x.w - m;
    float v = d0 * d0 + d1 * d1 + d2 * d2 + d3 * d3;
    #pragma unroll
    for (int o = 32; o > 0; o >>= 1) v += __shfl_xor(v, o, 64);
    float rs = rsqrtf(v * (1.f / 256.f) + 1e-5f);
    float4 wv = ld4(&w[lane << 2]);
    float4 bv = ld4(&b[lane << 2]);
    float4 o4;
    o4.x = d0 * rs * wv.x + bv.x;
    o4.y = d1 * rs * wv.y + bv.y;
    o4.z = d2 * rs * wv.z + bv.z;
    o4.w = d3 * rs * wv.w + bv.w;
    *(float4*)&src[base] = o4;
}

// ---------------- (HW, 256) -> (256, HW) transpose ----------------
__global__ void tr_k(const float* __restrict__ src, float* __restrict__ dst, int HW)
{
    __shared__ float t[32][33];
    int p0 = blockIdx.x * 32, c0 = blockIdx.y * 32;
    int x = threadIdx.x, y = threadIdx.y;
    for (int i = y; i < 32; i += 8)
        t[i][x] = src[(size_t)(p0 + i) * 256 + c0 + x];
    __syncthreads();
    for (int i = y; i < 32; i += 8)
        dst[(size_t)(c0 + i) * HW + p0 + x] = t[x][i];
}

// ---------------- 3x3 SAME conv, 256->256, 64x64 ----------------
// block: 32 oc x (8y x 16x) tile; thread: 4 oc x 4 x-positions
__global__ __launch_bounds__(256) void conv3_k(const float* __restrict__ in,
                                               const float* __restrict__ wt,
                                               float* __restrict__ out)
{
    __shared__ float sIn[8][10][18];
    __shared__ float sW[8 * 9 * 32];
    const int tid = threadIdx.x;
    const int og = tid & 7;        // oc group: oc = oc0 + og*4 + j
    const int pg = tid >> 3;       // 32 position groups
    const int yy = pg >> 2;        // 0..7
    const int xq = (pg & 3) << 2;  // 0,4,8,12
    const int sb = blockIdx.x;     // 0..31
    const int x0 = (sb & 3) << 4;
    const int y0 = (sb >> 2) << 3;
    const int oc0 = blockIdx.y << 5;
    float acc[4][4] = {};

    for (int ic0 = 0; ic0 < 256; ic0 += 8) {
        for (int id = tid; id < 1440; id += 256) {
            int c = id % 18;
            int r = (id / 18) % 10;
            int ic = id / 180;
            int gx = x0 - 1 + c, gy = y0 - 1 + r;
            float v = 0.f;
            if (gx >= 0 && gx < 64 && gy >= 0 && gy < 64)
                v = in[(size_t)(ic0 + ic) * 4096 + gy * 64 + gx];
            sIn[ic][r][c] = v;
        }
        for (int id = tid; id < 2304; id += 256) {
            int oc = id & 31;
            int k = (id >> 5) % 9;
            int ic = id / 288;
            sW[id] = wt[((size_t)(oc0 + oc) * 256 + ic0 + ic) * 9 + k];
        }
        __syncthreads();
        #pragma unroll
        for (int ic = 0; ic < 8; ic++) {
            #pragma unroll
            for (int ky = 0; ky < 3; ky++) {
                float iv[6];
                #pragma unroll
                for (int u = 0; u < 6; u++) iv[u] = sIn[ic][yy + ky][xq + u];
                #pragma unroll
                for (int kx = 0; kx < 3; kx++) {
                    float4 wv = *(const float4*)&sW[((ic * 9 + ky * 3 + kx) << 5) + (og << 2)];
                    float wa[4] = {wv.x, wv.y, wv.z, wv.w};
                    #pragma unroll
                    for (int j = 0; j < 4; j++)
                        #pragma unroll
                        for (int t = 0; t < 4; t++)
                            acc[j][t] = fmaf(wa[j], iv[kx + t], acc[j][t]);
                }
            }
        }
        __syncthreads();
    }
    #pragma unroll
    for (int j = 0; j < 4; j++) {
        int oc = oc0 + (og << 2) + j;
        float4 o4 = make_float4(acc[j][0], acc[j][1], acc[j][2], acc[j][3]);
        *(float4*)&out[(size_t)oc * 4096 + (y0 + yy) * 64 + x0 + xq] = o4;
    }
}

// ---------------- groupnorm stats (32 groups x 8ch x 4096) ----------------
__global__ __launch_bounds__(256) void gnstats_k(const float* __restrict__ x, float* __restrict__ st)
{
    int g = blockIdx.x;
    const float* p = x + (size_t)g * 8 * 4096;
    float s = 0.f, ss = 0.f;
    for (int i = threadIdx.x * 4; i < 32768; i += 1024) {
        float4 v = ld4(&p[i]);
        s  += v.x + v.y + v.z + v.w;
        ss += v.x * v.x + v.y * v.y + v.z * v.z + v.w * v.w;
    }
    #pragma unroll
    for (int o = 32; o > 0; o >>= 1) {
        s  += __shfl_xor(s, o, 64);
        ss += __shfl_xor(ss, o, 64);
    }
    __shared__ float rs[4], rss[4];
    int wid = threadIdx.x >> 6;
    if ((threadIdx.x & 63) == 0) { rs[wid] = s; rss[wid] = ss; }
    __syncthreads();
    if (threadIdx.x == 0) {
        float S = rs[0] + rs[1] + rs[2] + rs[3];
        float SS = rss[0] + rss[1] + rss[2] + rss[3];
        float m = S * (1.f / 32768.f);
        float var = SS * (1.f / 32768.f) - m * m;
        st[g * 2] = m;
        st[g * 2 + 1] = rsqrtf(var + 1e-5f);
    }
}

// ---------------- groupnorm apply + relu ----------------
__global__ void gnapply_k(const float* __restrict__ x, const float* __restrict__ st,
                          const float* __restrict__ w, const float* __restrict__ b,
                          float* __restrict__ o)
{
    int i = blockIdx.x * blockDim.x + threadIdx.x;  // float4 index
    if (i >= 262144) return;
    int c = i >> 10;       // / 1024 (4096 floats per channel / 4)
    int g = c >> 3;
    float m = st[g * 2], rs = st[g * 2 + 1];
    float sw = w[c], sb = b[c];
    float4 v = ld4(&x[(size_t)i << 2]);
    float4 r;
    r.x = fmaxf((v.x - m) * rs * sw + sb, 0.f);
    r.y = fmaxf((v.y - m) * rs * sw + sb, 0.f);
    r.z = fmaxf((v.z - m) * rs * sw + sb, 0.f);
    r.w = fmaxf((v.w - m) * rs * sw + sb, 0.f);
    *(float4*)&o[(size_t)i << 2] = r;
}

// ---------------- host launcher ----------------
extern "C" void kernel_launch(void* const* d_in, const int* in_sizes, int n_in,
                              void* d_out, int out_size, void* d_ws, size_t ws_size,
                              hipStream_t stream)
{
    (void)in_sizes; (void)n_in; (void)out_size; (void)ws_size;
    const float* feat0 = (const float*)d_in[0];
    const float* feat1 = (const float*)d_in[1];
    const float* feat2 = (const float*)d_in[2];
    const float* in0_w = (const float*)d_in[3];
    const float* in0_b = (const float*)d_in[4];
    const float* in1_w = (const float*)d_in[5];
    const float* in1_b = (const float*)d_in[6];
    const float* in2_w = (const float*)d_in[7];
    const float* in2_b = (const float*)d_in[8];
    const float* off_w = (const float*)d_in[9];
    const float* off_b = (const float*)d_in[10];
    const float* aw_w  = (const float*)d_in[11];
    const float* aw_b  = (const float*)d_in[12];
    const float* vp_w  = (const float*)d_in[13];
    const float* vp_b  = (const float*)d_in[14];
    const float* op_w  = (const float*)d_in[15];
    const float* op_b  = (const float*)d_in[16];
    const float* n1_w  = (const float*)d_in[17];
    const float* n1_b  = (const float*)d_in[18];
    const float* ff1_w = (const float*)d_in[19];
    const float* ff1_b = (const float*)d_in[20];
    const float* ff2_w = (const float*)d_in[21];
    const float* ff2_b = (const float*)d_in[22];
    const float* n2_w  = (const float*)d_in[23];
    const float* n2_b  = (const float*)d_in[24];
    const float* fn_w  = (const float*)d_in[25];
    const float* fn_b  = (const float*)d_in[26];
    const float* lat_w = (const float*)d_in[27];
    const float* lat_b = (const float*)d_in[28];
    const float* out_w = (const float*)d_in[29];
    const float* gnw   = (const float*)d_in[30];
    const float* gnb   = (const float*)d_in[31];
    float* out = (float*)d_out;

    float* ws   = (float*)d_ws;
    float* src  = ws;                    // 1376256
    float* pos  = src  + 1376256;        // 1376256
    float* qb   = pos  + 1376256;        // 1376256
    float* val  = qb   + 1376256;        // 1376256
    float* msd  = val  + 1376256;        // 1376256
    float* tmp  = msd  + 1376256;        // 1376256
    float* offb = tmp  + 1376256;        // 1032192
    float* awb  = offb + 1032192;        // 516096
    float* ffh  = awb  + 516096;         // 5505024
    float* ping = ffh  + 5505024;        // 1048576
    float* pong = ping + 1048576;        // 1048576
    float* stats= pong + 1048576;        // 64

    // input projections -> src (L, 256)
    gemm_k<true,false,false,false><<<dim3(4,64),256,0,stream>>>(feat0,4096, in0_w,256,  in0_b, src,            256, 4096,256,256);
    gemm_k<true,false,false,false><<<dim3(4,16),256,0,stream>>>(feat1,1024, in1_w,512,  in1_b, src+4096*256,   256, 1024,256,512);
    gemm_k<true,false,false,false><<<dim3(4,4), 256,0,stream>>>(feat2,256,  in2_w,1024, in2_b, src+5120*256,   256, 256, 256,1024);
    posenc_k<<<2688,256,0,stream>>>(pos);

    for (int i = 0; i < 6; i++) {
        add_k<<<1344,256,0,stream>>>(src, pos, qb, 344064);
        gemm_k<false,false,false,false><<<dim3(3,84),256,0,stream>>>(qb,256,  off_w+i*49152, 256,  off_b+i*192,  offb,192, 5376,192, 256);
        gemm_k<false,false,false,false><<<dim3(2,84),256,0,stream>>>(qb,256,  aw_w+i*24576,  256,  aw_b+i*96,    awb, 96,  5376,96,  256);
        softmax12_k<<<168,256,0,stream>>>(awb);
        gemm_k<false,false,false,false><<<dim3(4,84),256,0,stream>>>(src,256, vp_w+i*65536,  256,  vp_b+i*256,   val, 256, 5376,256, 256);
        msdef_k<<<5376,256,0,stream>>>(val, offb, awb, msd);
        gemm_k<false,false,false,false><<<dim3(4,84),256,0,stream>>>(msd,256, op_w+i*65536,  256,  op_b+i*256,   tmp, 256, 5376,256, 256);
        ln_k<true><<<1344,256,0,stream>>>(src, tmp, n1_w+i*256, n1_b+i*256);
        gemm_k<false,false,true ,false><<<dim3(16,84),256,0,stream>>>(src,256, ff1_w+i*262144,256, ff1_b+i*1024, ffh,1024, 5376,1024,256);
        gemm_k<false,false,false,false><<<dim3(4,84), 256,0,stream>>>(ffh,1024,ff2_w+i*262144,1024,ff2_b+i*256,  tmp,256,  5376,256,1024);
        ln_k<true><<<1344,256,0,stream>>>(src, tmp, n2_w+i*256, n2_b+i*256);
    }
    ln_k<false><<<1344,256,0,stream>>>(src, nullptr, fn_w, fn_b);

    // mems -> d_out (NCHW)
    tr_k<<<dim3(128,8),dim3(32,8),0,stream>>>(src,          out+1048576, 4096);
    tr_k<<<dim3(32,8), dim3(32,8),0,stream>>>(src+1048576,  out+2097152, 1024);
    tr_k<<<dim3(8,8),  dim3(32,8),0,stream>>>(src+1310720,  out+2359296, 256);

    // lateral 1x1 conv on mems[0] (row bias)
    gemm_k<false,true,false,true><<<dim3(64,4),256,0,stream>>>(lat_w,256, out+1048576,4096, lat_b, ping,4096, 256,4096,256);

    // 3x (conv3x3 -> groupnorm -> relu)
    for (int c = 0; c < 3; c++) {
        conv3_k<<<dim3(32,8),256,0,stream>>>(ping, out_w + (size_t)c*589824, pong);
        gnstats_k<<<32,256,0,stream>>>(pong, stats);
        gnapply_k<<<1024,256,0,stream>>>(pong, stats, gnw + c*256, gnb + c*256, (c == 2) ? out : ping);
    }
}

// Round 3
// 1266.823 us; speedup vs baseline: 1.9714x; 1.9714x over previous
//
#include <hip/hip_runtime.h>
#include <math.h>

#define LTOT 5376

typedef __attribute__((ext_vector_type(8))) __bf16 bf16x8;
typedef __attribute__((ext_vector_type(4))) float f32x4;
typedef __attribute__((ext_vector_type(8))) unsigned short us8;
typedef __attribute__((ext_vector_type(4))) unsigned short us4;

static __device__ __forceinline__ float4 ld4(const float* p) { return *(const float4*)p; }

static __device__ __forceinline__ unsigned short f2bf(float f) {
    unsigned int u = __float_as_uint(f);
    return (unsigned short)((u + 0x7fffu + ((u >> 16) & 1u)) >> 16);
}

// ---------------- bf16 MFMA GEMM ----------------
// C(M,N) = A(M,K)bf16 @ B(N,K)bf16^T + bias(N)
// 64x64 tile, BK=32, 256 threads = 4 waves (2x2), each wave 32x32.
// OMODE: 0 = f32 out (C1), 1 = bf16 out (C2), 2 = both
template<int OMODE, bool RELU>
__global__ __launch_bounds__(256) void bgemm_k(
    const unsigned short* __restrict__ A,
    const unsigned short* __restrict__ B,
    const float* __restrict__ bias,
    float* __restrict__ C1,
    unsigned short* __restrict__ C2,
    int M, int N, int K)
{
    __shared__ unsigned short As[64 * 32];
    __shared__ unsigned short Bs[64 * 32];
    const int tid  = threadIdx.x;
    const int m0   = blockIdx.y * 64;
    const int n0   = blockIdx.x * 64;
    const int wave = tid >> 6;
    const int lane = tid & 63;
    const int wm   = (wave >> 1) * 32;
    const int wn   = (wave & 1) * 32;
    const int fr   = lane & 15;
    const int ko   = lane >> 4;

    // staging: thread t -> row t>>2, k-chunk (t&3)*8, swizzled chunk slot
    const int srow  = tid >> 2;
    const int skoff = tid & 3;
    const int sdst  = srow * 32 + (((skoff ^ ((srow >> 1) & 3))) << 3);
    const int arow  = m0 + srow;
    int brow = n0 + srow; if (brow > N - 1) brow = N - 1;

    f32x4 acc[2][2] = {};

    for (int k0 = 0; k0 < K; k0 += 32) {
        us8 av = *(const us8*)&A[(size_t)arow * K + k0 + (skoff << 3)];
        us8 bv = *(const us8*)&B[(size_t)brow * K + k0 + (skoff << 3)];
        __syncthreads();
        *(us8*)&As[sdst] = av;
        *(us8*)&Bs[sdst] = bv;
        __syncthreads();
        bf16x8 af[2], bfr[2];
        #pragma unroll
        for (int i = 0; i < 2; i++) {
            int r = wm + i * 16 + fr;
            af[i] = *(const bf16x8*)&As[r * 32 + ((ko ^ ((r >> 1) & 3)) << 3)];
            int c = wn + i * 16 + fr;
            bfr[i] = *(const bf16x8*)&Bs[c * 32 + ((ko ^ ((c >> 1) & 3)) << 3)];
        }
        #pragma unroll
        for (int i = 0; i < 2; i++)
            #pragma unroll
            for (int j = 0; j < 2; j++)
                acc[i][j] = __builtin_amdgcn_mfma_f32_16x16x32_bf16(af[i], bfr[j], acc[i][j], 0, 0, 0);
    }

    #pragma unroll
    for (int j = 0; j < 2; j++) {
        int col = n0 + wn + j * 16 + fr;
        if (col >= N) continue;
        float cb = bias[col];
        #pragma unroll
        for (int i = 0; i < 2; i++) {
            #pragma unroll
            for (int r = 0; r < 4; r++) {
                int row = m0 + wm + i * 16 + ko * 4 + r;
                float v = acc[i][j][r] + cb;
                if (RELU) v = fmaxf(v, 0.f);
                size_t off = (size_t)row * N + col;
                if (OMODE == 0) C1[off] = v;
                else if (OMODE == 1) C2[off] = f2bf(v);
                else { C1[off] = v; C2[off] = f2bf(v); }
            }
        }
    }
}

// ---------------- fp32 -> bf16 flat convert (4/thread) ----------------
__global__ void cvt4_k(const float* __restrict__ s, unsigned short* __restrict__ d, int n4)
{
    int i = blockIdx.x * blockDim.x + threadIdx.x;
    if (i >= n4) return;
    float4 v = ld4(&s[(size_t)i << 2]);
    us4 r = { f2bf(v.x), f2bf(v.y), f2bf(v.z), f2bf(v.w) };
    *(us4*)&d[(size_t)i << 2] = r;
}

// ---------------- (Ci,P) fp32 -> (P,Ci) bf16 transpose ----------------
__global__ void cvtT_k(const float* __restrict__ src, unsigned short* __restrict__ dst, int Ci, int P)
{
    __shared__ float t[32][33];
    int c0 = blockIdx.y * 32, p0 = blockIdx.x * 32;
    int x = threadIdx.x, y = threadIdx.y;
    for (int i = y; i < 32; i += 8)
        t[i][x] = src[(size_t)(c0 + i) * P + p0 + x];
    __syncthreads();
    for (int i = y; i < 32; i += 8)
        dst[(size_t)(p0 + i) * Ci + c0 + x] = f2bf(t[x][i]);
}

// ---------------- sine positional encoding ----------------
__global__ void posenc_k(float* __restrict__ pos)
{
    int idx = blockIdx.x * blockDim.x + threadIdx.x;
    if (idx >= LTOT * 128) return;
    int l = idx >> 7;
    int pr = idx & 127;
    int half = pr >> 6;
    int j = pr & 63;
    int HW, sh, p;
    if (l < 4096)      { HW = 64; sh = 6; p = l; }
    else if (l < 5120) { HW = 32; sh = 5; p = l - 4096; }
    else               { HW = 16; sh = 4; p = l - 5120; }
    int y = p >> sh;
    int x = p & (HW - 1);
    float T = powf(10000.f, (float)j * (1.f / 64.f));
    float coord = (half == 0) ? (float)(y + 1) : (float)(x + 1);
    float v = coord / ((float)HW + 1e-6f) * 6.283185307179586f;
    float arg = v / T;
    size_t base = (size_t)l * 256 + half * 128 + (j << 1);
    pos[base]     = sinf(arg);
    pos[base + 1] = cosf(arg);
}

// ---------------- q = src + pos -> bf16 ----------------
__global__ void addb_k(const float* __restrict__ a, const float* __restrict__ b,
                       unsigned short* __restrict__ o, int n4)
{
    int i = blockIdx.x * blockDim.x + threadIdx.x;
    if (i >= n4) return;
    float4 x = ld4(&a[(size_t)i << 2]);
    float4 y = ld4(&b[(size_t)i << 2]);
    us4 r = { f2bf(x.x + y.x), f2bf(x.y + y.y), f2bf(x.z + y.z), f2bf(x.w + y.w) };
    *(us4*)&o[(size_t)i << 2] = r;
}

// ---------------- softmax over 12 (per l, head) ----------------
__global__ void softmax12_k(float* __restrict__ aw)
{
    int r = blockIdx.x * blockDim.x + threadIdx.x;
    if (r >= LTOT * 8) return;
    float* p = aw + (size_t)r * 12;
    float mx = -1e30f;
    float v[12];
    #pragma unroll
    for (int j = 0; j < 12; j++) { v[j] = p[j]; mx = fmaxf(mx, v[j]); }
    float s = 0.f;
    #pragma unroll
    for (int j = 0; j < 12; j++) { v[j] = expf(v[j] - mx); s += v[j]; }
    float inv = 1.f / s;
    #pragma unroll
    for (int j = 0; j < 12; j++) p[j] = v[j] * inv;
}

// ---------------- multi-scale deformable sampling (out: bf16) ----------------
__global__ __launch_bounds__(256) void msdef_k(
    const float* __restrict__ val, const float* __restrict__ off,
    const float* __restrict__ aw, unsigned short* __restrict__ out)
{
    const int l = blockIdx.x;
    const int tid = threadIdx.x;
    __shared__ float soff[192];
    __shared__ float saw[96];
    if (tid < 192) soff[tid] = off[(size_t)l * 192 + tid];
    if (tid < 96)  saw[tid]  = aw[(size_t)l * 96 + tid];
    __syncthreads();
    const int h = tid >> 5;

    float rx, ry;
    {
        int HW, sh, p;
        if (l < 4096)      { HW = 64; sh = 6; p = l; }
        else if (l < 5120) { HW = 32; sh = 5; p = l - 4096; }
        else               { HW = 16; sh = 4; p = l - 5120; }
        int y = p >> sh;
        int x = p & (HW - 1);
        rx = (x + 0.5f) / (float)HW;
        ry = (y + 0.5f) / (float)HW;
    }

    const int starts[3] = {0, 4096, 5120};
    const int dims[3]   = {64, 32, 16};
    float acc = 0.f;
    #pragma unroll
    for (int s = 0; s < 3; s++) {
        const int D = dims[s];
        const int st = starts[s];
        #pragma unroll
        for (int pt = 0; pt < 4; pt++) {
            int ob = h * 24 + s * 8 + (pt << 1);
            float a  = saw[h * 12 + (s << 2) + pt];
            float px = rx * D + soff[ob]     - 0.5f;
            float py = ry * D + soff[ob + 1] - 0.5f;
            float x0f = floorf(px), y0f = floorf(py);
            float lx = px - x0f, ly = py - y0f;
            int x0 = (int)x0f, y0 = (int)y0f;
            float w00 = a * (1.f - lx) * (1.f - ly);
            float w10 = a * lx * (1.f - ly);
            float w01 = a * (1.f - lx) * ly;
            float w11 = a * lx * ly;
            #pragma unroll
            for (int cy = 0; cy < 2; cy++) {
                int yi = y0 + cy;
                if (yi < 0 || yi >= D) continue;
                #pragma unroll
                for (int cx = 0; cx < 2; cx++) {
                    int xi = x0 + cx;
                    if (xi < 0 || xi >= D) continue;
                    float w = cy ? (cx ? w11 : w01) : (cx ? w10 : w00);
                    acc += w * val[((size_t)(st + yi * D + xi)) * 256 + tid];
                }
            }
        }
    }
    out[(size_t)l * 256 + tid] = f2bf(acc);
}

// ---------------- layernorm (+residual), in-place fp32 + bf16 copy ----------------
template<bool HAS_ADD>
__global__ __launch_bounds__(256) void ln_k(float* __restrict__ src, const float* __restrict__ add,
                                            const float* __restrict__ w, const float* __restrict__ b,
                                            unsigned short* __restrict__ outb)
{
    int row = blockIdx.x * 4 + (threadIdx.x >> 6);
    int lane = threadIdx.x & 63;
    size_t base = (size_t)row * 256 + (lane << 2);
    float4 x = ld4(&src[base]);
    if (HAS_ADD) {
        float4 a = ld4(&add[base]);
        x.x += a.x; x.y += a.y; x.z += a.z; x.w += a.w;
    }
    float s = x.x + x.y + x.z + x.w;
    #pragma unroll
    for (int o = 32; o > 0; o >>= 1) s += __shfl_xor(s, o, 64);
    float m = s * (1.f / 256.f);
    float d0 = x.x - m, d1 = x.y - m, d2 = x.z - m, d3 = x.w - m;
    float v = d0 * d0 + d1 * d1 + d2 * d2 + d3 * d3;
    #pragma unroll
    for (int o = 32; o > 0; o >>= 1) v += __shfl_xor(v, o, 64);
    float rs = rsqrtf(v * (1.f / 256.f) + 1e-5f);
    float4 wv = ld4(&w[lane << 2]);
    float4 bv = ld4(&b[lane << 2]);
    float4 o4;
    o4.x = d0 * rs * wv.x + bv.x;
    o4.y = d1 * rs * wv.y + bv.y;
    o4.z = d2 * rs * wv.z + bv.z;
    o4.w = d3 * rs * wv.w + bv.w;
    *(float4*)&src[base] = o4;
    us4 r = { f2bf(o4.x), f2bf(o4.y), f2bf(o4.z), f2bf(o4.w) };
    *(us4*)&outb[base] = r;
}

// ---------------- (HW,256) -> (256,HW) transpose (fp32) ----------------
__global__ void tr_k(const float* __restrict__ src, float* __restrict__ dst, int HW)
{
    __shared__ float t[32][33];
    int p0 = blockIdx.x * 32, c0 = blockIdx.y * 32;
    int x = threadIdx.x, y = threadIdx.y;
    for (int i = y; i < 32; i += 8)
        t[i][x] = src[(size_t)(p0 + i) * 256 + c0 + x];
    __syncthreads();
    for (int i = y; i < 32; i += 8)
        dst[(size_t)(c0 + i) * HW + p0 + x] = t[x][i];
}

// ---------------- 3x3 SAME conv, 256->256, 64x64, 16-oc blocks ----------------
__global__ __launch_bounds__(256) void conv3_k(const float* __restrict__ in,
                                               const float* __restrict__ wt,
                                               float* __restrict__ out)
{
    __shared__ float sIn[8][10][18];
    __shared__ float sW[8 * 9 * 16];
    const int tid = threadIdx.x;
    const int og = tid & 3;         // oc = oc0 + og*4 + j
    const int pg = tid >> 2;        // 0..63
    const int yy = pg >> 3;         // 0..7
    const int xd = (pg & 7) << 1;   // 0,2,..,14
    const int sb = blockIdx.x;      // 0..31
    const int x0 = (sb & 3) << 4;
    const int y0 = (sb >> 2) << 3;
    const int oc0 = blockIdx.y << 4;
    float acc[4][2] = {};

    for (int ic0 = 0; ic0 < 256; ic0 += 8) {
        for (int id = tid; id < 1440; id += 256) {
            int c = id % 18;
            int r = (id / 18) % 10;
            int ic = id / 180;
            int gx = x0 - 1 + c, gy = y0 - 1 + r;
            float v = 0.f;
            if (gx >= 0 && gx < 64 && gy >= 0 && gy < 64)
                v = in[(size_t)(ic0 + ic) * 4096 + gy * 64 + gx];
            sIn[ic][r][c] = v;
        }
        for (int id = tid; id < 1152; id += 256) {
            int oc = id & 15;
            int k = (id >> 4) % 9;
            int ic = id / 144;
            sW[id] = wt[((size_t)(oc0 + oc) * 256 + ic0 + ic) * 9 + k];
        }
        __syncthreads();
        #pragma unroll
        for (int ic = 0; ic < 8; ic++) {
            #pragma unroll
            for (int ky = 0; ky < 3; ky++) {
                float iv[4];
                #pragma unroll
                for (int u = 0; u < 4; u++) iv[u] = sIn[ic][yy + ky][xd + u];
                #pragma unroll
                for (int kx = 0; kx < 3; kx++) {
                    float4 wv = *(const float4*)&sW[((ic * 9 + ky * 3 + kx) << 4) + (og << 2)];
                    float wa[4] = {wv.x, wv.y, wv.z, wv.w};
                    #pragma unroll
                    for (int j = 0; j < 4; j++)
                        #pragma unroll
                        for (int t = 0; t < 2; t++)
                            acc[j][t] = fmaf(wa[j], iv[kx + t], acc[j][t]);
                }
            }
        }
        __syncthreads();
    }
    #pragma unroll
    for (int j = 0; j < 4; j++) {
        int oc = oc0 + (og << 2) + j;
        *(float2*)&out[(size_t)oc * 4096 + (y0 + yy) * 64 + x0 + xd] =
            make_float2(acc[j][0], acc[j][1]);
    }
}

// ---------------- groupnorm stats ----------------
__global__ __launch_bounds__(256) void gnstats_k(const float* __restrict__ x, float* __restrict__ st)
{
    int g = blockIdx.x;
    const float* p = x + (size_t)g * 8 * 4096;
    float s = 0.f, ss = 0.f;
    for (int i = threadIdx.x * 4; i < 32768; i += 1024) {
        float4 v = ld4(&p[i]);
        s  += v.x + v.y + v.z + v.w;
        ss += v.x * v.x + v.y * v.y + v.z * v.z + v.w * v.w;
    }
    #pragma unroll
    for (int o = 32; o > 0; o >>= 1) {
        s  += __shfl_xor(s, o, 64);
        ss += __shfl_xor(ss, o, 64);
    }
    __shared__ float rs[4], rss[4];
    int wid = threadIdx.x >> 6;
    if ((threadIdx.x & 63) == 0) { rs[wid] = s; rss[wid] = ss; }
    __syncthreads();
    if (threadIdx.x == 0) {
        float S = rs[0] + rs[1] + rs[2] + rs[3];
        float SS = rss[0] + rss[1] + rss[2] + rss[3];
        float m = S * (1.f / 32768.f);
        float var = SS * (1.f / 32768.f) - m * m;
        st[g * 2] = m;
        st[g * 2 + 1] = rsqrtf(var + 1e-5f);
    }
}

// ---------------- groupnorm apply + relu ----------------
__global__ void gnapply_k(const float* __restrict__ x, const float* __restrict__ st,
                          const float* __restrict__ w, const float* __restrict__ b,
                          float* __restrict__ o)
{
    int i = blockIdx.x * blockDim.x + threadIdx.x;
    if (i >= 262144) return;
    int c = i >> 10;
    int g = c >> 3;
    float m = st[g * 2], rs = st[g * 2 + 1];
    float sw = w[c], sb = b[c];
    float4 v = ld4(&x[(size_t)i << 2]);
    float4 r;
    r.x = fmaxf((v.x - m) * rs * sw + sb, 0.f);
    r.y = fmaxf((v.y - m) * rs * sw + sb, 0.f);
    r.z = fmaxf((v.z - m) * rs * sw + sb, 0.f);
    r.w = fmaxf((v.w - m) * rs * sw + sb, 0.f);
    *(float4*)&o[(size_t)i << 2] = r;
}

// ---------------- host launcher ----------------
extern "C" void kernel_launch(void* const* d_in, const int* in_sizes, int n_in,
                              void* d_out, int out_size, void* d_ws, size_t ws_size,
                              hipStream_t stream)
{
    (void)in_sizes; (void)n_in; (void)out_size; (void)ws_size;
    const float* feat0 = (const float*)d_in[0];
    const float* feat1 = (const float*)d_in[1];
    const float* feat2 = (const float*)d_in[2];
    const float* in0_w = (const float*)d_in[3];
    const float* in0_b = (const float*)d_in[4];
    const float* in1_w = (const float*)d_in[5];
    const float* in1_b = (const float*)d_in[6];
    const float* in2_w = (const float*)d_in[7];
    const float* in2_b = (const float*)d_in[8];
    const float* off_w = (const float*)d_in[9];
    const float* off_b = (const float*)d_in[10];
    const float* aw_w  = (const float*)d_in[11];
    const float* aw_b  = (const float*)d_in[12];
    const float* vp_w  = (const float*)d_in[13];
    const float* vp_b  = (const float*)d_in[14];
    const float* op_w  = (const float*)d_in[15];
    const float* op_b  = (const float*)d_in[16];
    const float* n1_w  = (const float*)d_in[17];
    const float* n1_b  = (const float*)d_in[18];
    const float* ff1_w = (const float*)d_in[19];
    const float* ff1_b = (const float*)d_in[20];
    const float* ff2_w = (const float*)d_in[21];
    const float* ff2_b = (const float*)d_in[22];
    const float* n2_w  = (const float*)d_in[23];
    const float* n2_b  = (const float*)d_in[24];
    const float* fn_w  = (const float*)d_in[25];
    const float* fn_b  = (const float*)d_in[26];
    const float* lat_w = (const float*)d_in[27];
    const float* lat_b = (const float*)d_in[28];
    const float* out_w = (const float*)d_in[29];
    const float* gnw   = (const float*)d_in[30];
    const float* gnb   = (const float*)d_in[31];
    float* out = (float*)d_out;

    // ---- workspace layout (total ~57.3 MB; round-1's 69.6 MB was proven safe,
    // round-2's 73.5 MB diverged post-timing => keep well under 69 MB) ----
    float* ws    = (float*)d_ws;
    float* src   = ws;               // 1376256
    float* pos   = src  + 1376256;   // 1376256  (reused as conv pong after encoder)
    float* tmp   = pos  + 1376256;   // 1376256  (reused as conv ping after encoder)
    float* val   = tmp  + 1376256;   // 1376256  (reused as latT after encoder)
    float* offb  = val  + 1376256;   // 1032192
    float* awb   = offb + 1032192;   // 516096
    float* stats = awb  + 516096;    // 64
    float* latT  = val;              // alias (val dead after last msdef)
    float* ping  = tmp;              // alias (tmp dead after last ff2/ln)
    float* pong  = pos;              // alias (pos dead after last addb)

    unsigned short* ub = (unsigned short*)(stats + 64);
    unsigned short* srcb  = ub; ub += 1376256;
    unsigned short* qbb   = ub; ub += 1376256;
    unsigned short* msdb  = ub; ub += 1376256;
    unsigned short* ffhb  = ub; ub += 5505024;  // also hosts fT0/1/2 during setup
    unsigned short* w_off = ub; ub += 294912;
    unsigned short* w_aw  = ub; ub += 147456;
    unsigned short* w_vp  = ub; ub += 393216;
    unsigned short* w_op  = ub; ub += 393216;
    unsigned short* w_ff1 = ub; ub += 1572864;
    unsigned short* w_ff2 = ub; ub += 1572864;
    unsigned short* w_in0 = ub; ub += 65536;
    unsigned short* w_in1 = ub; ub += 131072;
    unsigned short* w_in2 = ub; ub += 262144;
    unsigned short* w_lat = ub; ub += 65536;

    // fT* alias into ffhb: used only by the input projections, which run
    // before the first ff1 GEMM (the first writer of ffhb).
    unsigned short* fT0 = ffhb;            // 1048576
    unsigned short* fT1 = ffhb + 1048576;  // 524288
    unsigned short* fT2 = ffhb + 1572864;  // 262144

    // ---- setup: weight conversions, feature transposes, pos enc ----
    cvt4_k<<<288, 256, 0, stream>>>(off_w, w_off, 73728);
    cvt4_k<<<144, 256, 0, stream>>>(aw_w,  w_aw,  36864);
    cvt4_k<<<384, 256, 0, stream>>>(vp_w,  w_vp,  98304);
    cvt4_k<<<384, 256, 0, stream>>>(op_w,  w_op,  98304);
    cvt4_k<<<1536,256, 0, stream>>>(ff1_w, w_ff1, 393216);
    cvt4_k<<<1536,256, 0, stream>>>(ff2_w, w_ff2, 393216);
    cvt4_k<<<64,  256, 0, stream>>>(in0_w, w_in0, 16384);
    cvt4_k<<<128, 256, 0, stream>>>(in1_w, w_in1, 32768);
    cvt4_k<<<256, 256, 0, stream>>>(in2_w, w_in2, 65536);
    cvt4_k<<<64,  256, 0, stream>>>(lat_w, w_lat, 16384);
    cvtT_k<<<dim3(128, 8), dim3(32, 8), 0, stream>>>(feat0, fT0, 256, 4096);
    cvtT_k<<<dim3(32, 16), dim3(32, 8), 0, stream>>>(feat1, fT1, 512, 1024);
    cvtT_k<<<dim3(8, 32),  dim3(32, 8), 0, stream>>>(feat2, fT2, 1024, 256);
    posenc_k<<<2688, 256, 0, stream>>>(pos);

    // ---- input projections -> src(f32) + srcb(bf16) ----
    bgemm_k<2,false><<<dim3(4,64), 256, 0, stream>>>(fT0, w_in0, in0_b, src,            srcb,            4096, 256, 256);
    bgemm_k<2,false><<<dim3(4,16), 256, 0, stream>>>(fT1, w_in1, in1_b, src + 4096*256, srcb + 4096*256, 1024, 256, 512);
    bgemm_k<2,false><<<dim3(4,4),  256, 0, stream>>>(fT2, w_in2, in2_b, src + 5120*256, srcb + 5120*256, 256,  256, 1024);

    // ---- encoder layers ----
    for (int i = 0; i < 6; i++) {
        addb_k<<<1344, 256, 0, stream>>>(src, pos, qbb, 344064);
        bgemm_k<0,false><<<dim3(3,84), 256, 0, stream>>>(qbb,  w_off + i*49152,  off_b + i*192,  offb, nullptr, 5376, 192, 256);
        bgemm_k<0,false><<<dim3(2,84), 256, 0, stream>>>(qbb,  w_aw  + i*24576,  aw_b  + i*96,   awb,  nullptr, 5376, 96,  256);
        softmax12_k<<<168, 256, 0, stream>>>(awb);
        bgemm_k<0,false><<<dim3(4,84), 256, 0, stream>>>(srcb, w_vp  + i*65536,  vp_b  + i*256,  val,  nullptr, 5376, 256, 256);
        msdef_k<<<5376, 256, 0, stream>>>(val, offb, awb, msdb);
        bgemm_k<0,false><<<dim3(4,84), 256, 0, stream>>>(msdb, w_op  + i*65536,  op_b  + i*256,  tmp,  nullptr, 5376, 256, 256);
        ln_k<true><<<1344, 256, 0, stream>>>(src, tmp, n1_w + i*256, n1_b + i*256, srcb);
        bgemm_k<1,true ><<<dim3(16,84),256, 0, stream>>>(srcb, w_ff1 + i*262144, ff1_b + i*1024, nullptr, ffhb, 5376, 1024, 256);
        bgemm_k<0,false><<<dim3(4,84), 256, 0, stream>>>(ffhb, w_ff2 + i*262144, ff2_b + i*256,  tmp,  nullptr, 5376, 256, 1024);
        ln_k<true><<<1344, 256, 0, stream>>>(src, tmp, n2_w + i*256, n2_b + i*256, srcb);
    }
    ln_k<false><<<1344, 256, 0, stream>>>(src, nullptr, fn_w, fn_b, srcb);

    // ---- mems -> d_out (NCHW) ----
    tr_k<<<dim3(128,8), dim3(32,8), 0, stream>>>(src,           out + 1048576, 4096);
    tr_k<<<dim3(32,8),  dim3(32,8), 0, stream>>>(src + 1048576, out + 2097152, 1024);
    tr_k<<<dim3(8,8),   dim3(32,8), 0, stream>>>(src + 1310720, out + 2359296, 256);

    // ---- lateral 1x1 (token-major GEMM) then transpose to NCHW ----
    bgemm_k<0,false><<<dim3(4,64), 256, 0, stream>>>(srcb, w_lat, lat_b, latT, nullptr, 4096, 256, 256);
    tr_k<<<dim3(128,8), dim3(32,8), 0, stream>>>(latT, ping, 4096);

    // ---- 3x (conv3x3 -> groupnorm -> relu) ----
    for (int c = 0; c < 3; c++) {
        conv3_k<<<dim3(32,16), 256, 0, stream>>>(ping, out_w + (size_t)c*589824, pong);
        gnstats_k<<<32, 256, 0, stream>>>(pong, stats);
        gnapply_k<<<1024, 256, 0, stream>>>(pong, stats, gnw + c*256, gnb + c*256, (c == 2) ? out : ping);
    }
}

// Round 4
// 729.746 us; speedup vs baseline: 3.4224x; 1.7360x over previous
//
#include <hip/hip_runtime.h>
#include <math.h>

#define LTOT 5376

typedef __attribute__((ext_vector_type(8))) __bf16 bf16x8;
typedef __attribute__((ext_vector_type(4))) float f32x4;
typedef __attribute__((ext_vector_type(8))) unsigned short us8;
typedef __attribute__((ext_vector_type(4))) unsigned short us4;

static __device__ __forceinline__ float4 ld4(const float* p) { return *(const float4*)p; }

static __device__ __forceinline__ unsigned short f2bf(float f) {
    unsigned int u = __float_as_uint(f);
    return (unsigned short)((u + 0x7fffu + ((u >> 16) & 1u)) >> 16);
}
static __device__ __forceinline__ float bf2f(unsigned short s) {
    return __uint_as_float(((unsigned int)s) << 16);
}

// ---------------- bf16 MFMA GEMM ----------------
// C(M,N) = A(M,K)bf16 @ B(N,K)bf16^T + bias(N)
// 64x64 tile, BK=32, 256 threads = 4 waves (2x2), each wave 32x32.
// OMODE: 0 = f32 out (C1), 1 = bf16 out (C2), 2 = both
template<int OMODE, bool RELU>
__global__ __launch_bounds__(256) void bgemm_k(
    const unsigned short* __restrict__ A,
    const unsigned short* __restrict__ B,
    const float* __restrict__ bias,
    float* __restrict__ C1,
    unsigned short* __restrict__ C2,
    int M, int N, int K)
{
    __shared__ unsigned short As[64 * 32];
    __shared__ unsigned short Bs[64 * 32];
    const int tid  = threadIdx.x;
    const int m0   = blockIdx.y * 64;
    const int n0   = blockIdx.x * 64;
    const int wave = tid >> 6;
    const int lane = tid & 63;
    const int wm   = (wave >> 1) * 32;
    const int wn   = (wave & 1) * 32;
    const int fr   = lane & 15;
    const int ko   = lane >> 4;

    const int srow  = tid >> 2;
    const int skoff = tid & 3;
    const int sdst  = srow * 32 + (((skoff ^ ((srow >> 1) & 3))) << 3);
    const int arow  = m0 + srow;
    int brow = n0 + srow; if (brow > N - 1) brow = N - 1;

    f32x4 acc[2][2] = {};

    for (int k0 = 0; k0 < K; k0 += 32) {
        us8 av = *(const us8*)&A[(size_t)arow * K + k0 + (skoff << 3)];
        us8 bv = *(const us8*)&B[(size_t)brow * K + k0 + (skoff << 3)];
        __syncthreads();
        *(us8*)&As[sdst] = av;
        *(us8*)&Bs[sdst] = bv;
        __syncthreads();
        bf16x8 af[2], bfr[2];
        #pragma unroll
        for (int i = 0; i < 2; i++) {
            int r = wm + i * 16 + fr;
            af[i] = *(const bf16x8*)&As[r * 32 + ((ko ^ ((r >> 1) & 3)) << 3)];
            int c = wn + i * 16 + fr;
            bfr[i] = *(const bf16x8*)&Bs[c * 32 + ((ko ^ ((c >> 1) & 3)) << 3)];
        }
        #pragma unroll
        for (int i = 0; i < 2; i++)
            #pragma unroll
            for (int j = 0; j < 2; j++)
                acc[i][j] = __builtin_amdgcn_mfma_f32_16x16x32_bf16(af[i], bfr[j], acc[i][j], 0, 0, 0);
    }

    #pragma unroll
    for (int j = 0; j < 2; j++) {
        int col = n0 + wn + j * 16 + fr;
        if (col >= N) continue;
        float cb = bias[col];
        #pragma unroll
        for (int i = 0; i < 2; i++) {
            #pragma unroll
            for (int r = 0; r < 4; r++) {
                int row = m0 + wm + i * 16 + ko * 4 + r;
                float v = acc[i][j][r] + cb;
                if (RELU) v = fmaxf(v, 0.f);
                size_t off = (size_t)row * N + col;
                if (OMODE == 0) C1[off] = v;
                else if (OMODE == 1) C2[off] = f2bf(v);
                else { C1[off] = v; C2[off] = f2bf(v); }
            }
        }
    }
}

// ---------------- fp32 -> bf16 flat convert ----------------
__global__ void cvt4_k(const float* __restrict__ s, unsigned short* __restrict__ d, int n4)
{
    int i = blockIdx.x * blockDim.x + threadIdx.x;
    if (i >= n4) return;
    float4 v = ld4(&s[(size_t)i << 2]);
    us4 r = { f2bf(v.x), f2bf(v.y), f2bf(v.z), f2bf(v.w) };
    *(us4*)&d[(size_t)i << 2] = r;
}

// ---------------- (Ci,P) fp32 -> (P,Ci) bf16 transpose ----------------
__global__ void cvtT_k(const float* __restrict__ src, unsigned short* __restrict__ dst, int Ci, int P)
{
    __shared__ float t[32][33];
    int c0 = blockIdx.y * 32, p0 = blockIdx.x * 32;
    int x = threadIdx.x, y = threadIdx.y;
    for (int i = y; i < 32; i += 8)
        t[i][x] = src[(size_t)(c0 + i) * P + p0 + x];
    __syncthreads();
    for (int i = y; i < 32; i += 8)
        dst[(size_t)(p0 + i) * Ci + c0 + x] = f2bf(t[x][i]);
}

// ---------------- pack off|aw weights+bias per layer (bf16 / f32) ----------------
__global__ void pack_oa_k(const float* __restrict__ off_w, const float* __restrict__ off_b,
                          const float* __restrict__ aw_w,  const float* __restrict__ aw_b,
                          unsigned short* __restrict__ w_oa, float* __restrict__ b_oa)
{
    int idx = blockIdx.x * blockDim.x + threadIdx.x;
    if (idx >= 6 * 288 * 256) return;
    int i = idx / 73728;
    int r = idx - i * 73728;
    int n = r >> 8;
    int k = r & 255;
    float v = (n < 192) ? off_w[((size_t)i * 192 + n) * 256 + k]
                        : aw_w[((size_t)i * 96 + (n - 192)) * 256 + k];
    w_oa[idx] = f2bf(v);
    if (k == 0)
        b_oa[i * 288 + n] = (n < 192) ? off_b[i * 192 + n] : aw_b[i * 96 + (n - 192)];
}

// ---------------- conv weight repack: out_w (3,256oc,256ic,3,3) f32 ->
// wcb[c][icc][oc][tap][sl] bf16 with slot swizzle sl-chunk = ko ^ ((oc>>1)&3) ----------------
__global__ void wconv_k(const float* __restrict__ out_w, unsigned short* __restrict__ wcb)
{
    int idx = blockIdx.x * blockDim.x + threadIdx.x;
    if (idx >= 3 * 589824) return;
    int c   = idx / 589824;
    int r   = idx - c * 589824;
    int icc = r / 73728;
    int r2  = r - icc * 73728;
    int oc  = r2 / 288;
    int r3  = r2 - oc * 288;
    int tap = r3 >> 5;
    int sl  = r3 & 31;
    int ic  = icc * 32 + (((sl >> 3) ^ ((oc >> 1) & 3)) << 3) + (sl & 7);
    wcb[idx] = f2bf(out_w[(((size_t)(c * 256 + oc)) * 256 + ic) * 9 + tap]);
}

// ---------------- sine positional encoding ----------------
__global__ void posenc_k(float* __restrict__ pos)
{
    int idx = blockIdx.x * blockDim.x + threadIdx.x;
    if (idx >= LTOT * 128) return;
    int l = idx >> 7;
    int pr = idx & 127;
    int half = pr >> 6;
    int j = pr & 63;
    int HW, sh, p;
    if (l < 4096)      { HW = 64; sh = 6; p = l; }
    else if (l < 5120) { HW = 32; sh = 5; p = l - 4096; }
    else               { HW = 16; sh = 4; p = l - 5120; }
    int y = p >> sh;
    int x = p & (HW - 1);
    float T = powf(10000.f, (float)j * (1.f / 64.f));
    float coord = (half == 0) ? (float)(y + 1) : (float)(x + 1);
    float v = coord / ((float)HW + 1e-6f) * 6.283185307179586f;
    float arg = v / T;
    size_t base = (size_t)l * 256 + half * 128 + (j << 1);
    pos[base]     = sinf(arg);
    pos[base + 1] = cosf(arg);
}

// ---------------- q = src + pos -> bf16 ----------------
__global__ void addb_k(const float* __restrict__ a, const float* __restrict__ b,
                       unsigned short* __restrict__ o, int n4)
{
    int i = blockIdx.x * blockDim.x + threadIdx.x;
    if (i >= n4) return;
    float4 x = ld4(&a[(size_t)i << 2]);
    float4 y = ld4(&b[(size_t)i << 2]);
    us4 r = { f2bf(x.x + y.x), f2bf(x.y + y.y), f2bf(x.z + y.z), f2bf(x.w + y.w) };
    *(us4*)&o[(size_t)i << 2] = r;
}

// ---------------- softmax over 12 per (l,h); aw lives at oab[l*288+192+h*12] ----------------
__global__ void softmax12_k(float* __restrict__ oab)
{
    int r = blockIdx.x * blockDim.x + threadIdx.x;
    if (r >= LTOT * 8) return;
    int l = r >> 3, h = r & 7;
    float* p = oab + (size_t)l * 288 + 192 + h * 12;
    float mx = -1e30f;
    float v[12];
    #pragma unroll
    for (int j = 0; j < 12; j++) { v[j] = p[j]; mx = fmaxf(mx, v[j]); }
    float s = 0.f;
    #pragma unroll
    for (int j = 0; j < 12; j++) { v[j] = expf(v[j] - mx); s += v[j]; }
    float inv = 1.f / s;
    #pragma unroll
    for (int j = 0; j < 12; j++) p[j] = v[j] * inv;
}

// ---------------- multi-scale deformable sampling ----------------
// valb: (L,256) bf16; oab: (L,288) f32 [off 192 | aw 96]; out: (L,256) bf16
// block = 256 thr = 8 positions x 32 thr; each thread: 1 head x 8 channels (us8)
__global__ __launch_bounds__(256) void msdef_k(
    const unsigned short* __restrict__ valb, const float* __restrict__ oab,
    unsigned short* __restrict__ out)
{
    __shared__ float sw[8 * 288];
    const int tid = threadIdx.x;
    const int bl = blockIdx.x;
    // stage 8 positions' off+aw rows (linear copy)
    #pragma unroll
    for (int id = tid; id < 576; id += 256)
        ((float4*)sw)[id] = ((const float4*)(oab + (size_t)bl * 2304))[id];
    __syncthreads();

    const int p = tid >> 5;
    const int t = tid & 31;
    const int l = bl * 8 + p;
    const int h = t >> 2;
    const int co = (t & 3) << 3;
    const float* mo = sw + p * 288;

    float rx, ry;
    {
        int HW, sh, q;
        if (l < 4096)      { HW = 64; sh = 6; q = l; }
        else if (l < 5120) { HW = 32; sh = 5; q = l - 4096; }
        else               { HW = 16; sh = 4; q = l - 5120; }
        int y = q >> sh;
        int x = q & (HW - 1);
        rx = (x + 0.5f) / (float)HW;
        ry = (y + 0.5f) / (float)HW;
    }

    const int starts[3] = {0, 4096, 5120};
    const int dims[3]   = {64, 32, 16};
    float acc[8] = {};
    #pragma unroll
    for (int s = 0; s < 3; s++) {
        const int D = dims[s];
        const int st = starts[s];
        #pragma unroll
        for (int pt = 0; pt < 4; pt++) {
            float a  = mo[192 + h * 12 + (s << 2) + pt];
            float px = rx * D + mo[h * 24 + (s << 3) + (pt << 1)]     - 0.5f;
            float py = ry * D + mo[h * 24 + (s << 3) + (pt << 1) + 1] - 0.5f;
            float x0f = floorf(px), y0f = floorf(py);
            float lx = px - x0f, ly = py - y0f;
            int x0 = (int)x0f, y0 = (int)y0f;
            float w00 = a * (1.f - lx) * (1.f - ly);
            float w10 = a * lx * (1.f - ly);
            float w01 = a * (1.f - lx) * ly;
            float w11 = a * lx * ly;
            #pragma unroll
            for (int cy = 0; cy < 2; cy++) {
                int yi = y0 + cy;
                if (yi < 0 || yi >= D) continue;
                #pragma unroll
                for (int cx = 0; cx < 2; cx++) {
                    int xi = x0 + cx;
                    if (xi < 0 || xi >= D) continue;
                    float w = cy ? (cx ? w11 : w01) : (cx ? w10 : w00);
                    us8 v = *(const us8*)&valb[((size_t)(st + yi * D + xi) << 8) + (h << 5) + co];
                    #pragma unroll
                    for (int e = 0; e < 8; e++)
                        acc[e] = fmaf(w, bf2f(v[e]), acc[e]);
                }
            }
        }
    }
    us8 r;
    #pragma unroll
    for (int e = 0; e < 8; e++) r[e] = f2bf(acc[e]);
    *(us8*)&out[((size_t)l << 8) + (h << 5) + co] = r;
}

// ---------------- layernorm (+residual), in-place fp32 + bf16 copy ----------------
template<bool HAS_ADD>
__global__ __launch_bounds__(256) void ln_k(float* __restrict__ src, const float* __restrict__ add,
                                            const float* __restrict__ w, const float* __restrict__ b,
                                            unsigned short* __restrict__ outb)
{
    int row = blockIdx.x * 4 + (threadIdx.x >> 6);
    int lane = threadIdx.x & 63;
    size_t base = (size_t)row * 256 + (lane << 2);
    float4 x = ld4(&src[base]);
    if (HAS_ADD) {
        float4 a = ld4(&add[base]);
        x.x += a.x; x.y += a.y; x.z += a.z; x.w += a.w;
    }
    float s = x.x + x.y + x.z + x.w;
    #pragma unroll
    for (int o = 32; o > 0; o >>= 1) s += __shfl_xor(s, o, 64);
    float m = s * (1.f / 256.f);
    float d0 = x.x - m, d1 = x.y - m, d2 = x.z - m, d3 = x.w - m;
    float v = d0 * d0 + d1 * d1 + d2 * d2 + d3 * d3;
    #pragma unroll
    for (int o = 32; o > 0; o >>= 1) v += __shfl_xor(v, o, 64);
    float rs = rsqrtf(v * (1.f / 256.f) + 1e-5f);
    float4 wv = ld4(&w[lane << 2]);
    float4 bv = ld4(&b[lane << 2]);
    float4 o4;
    o4.x = d0 * rs * wv.x + bv.x;
    o4.y = d1 * rs * wv.y + bv.y;
    o4.z = d2 * rs * wv.z + bv.z;
    o4.w = d3 * rs * wv.w + bv.w;
    *(float4*)&src[base] = o4;
    us4 r = { f2bf(o4.x), f2bf(o4.y), f2bf(o4.z), f2bf(o4.w) };
    *(us4*)&outb[base] = r;
}

// ---------------- (HW,256) -> (256,HW) transpose (fp32) ----------------
__global__ void tr_k(const float* __restrict__ src, float* __restrict__ dst, int HW)
{
    __shared__ float t[32][33];
    int p0 = blockIdx.x * 32, c0 = blockIdx.y * 32;
    int x = threadIdx.x, y = threadIdx.y;
    for (int i = y; i < 32; i += 8)
        t[i][x] = src[(size_t)(p0 + i) * 256 + c0 + x];
    __syncthreads();
    for (int i = y; i < 32; i += 8)
        dst[(size_t)(c0 + i) * HW + p0 + x] = t[x][i];
}

// ---------------- 3x3 conv via bf16 MFMA implicit GEMM ----------------
// inb: NHWC bf16 [4096][256]; wcb: packed bf16 [icc][oc][tap][sl]; out: NCHW f32
// block: 64px (4y x 16x) x 64oc, 4 waves 2x2, each wave 32px x 32oc
__global__ __launch_bounds__(256) void conv3b_k(const unsigned short* __restrict__ inb,
                                                const unsigned short* __restrict__ wcb,
                                                float* __restrict__ out)
{
    __shared__ __align__(16) unsigned char smem[43776];
    unsigned short* sIn = (unsigned short*)smem;          // 6*18*32 = 3456 elems (6912 B)
    unsigned short* sW  = (unsigned short*)(smem + 6912); // 64*9*32 = 18432 elems (36864 B)
    float* sO = (float*)smem;                             // 64*68 floats (17408 B), reused

    const int tid = threadIdx.x;
    const int mb = blockIdx.x;
    const int y0 = (mb >> 2) << 2;
    const int x0 = (mb & 3) << 4;
    const int oc0 = blockIdx.y << 6;
    const int wave = tid >> 6, lane = tid & 63;
    const int wm = (wave >> 1) * 32, wn = (wave & 1) * 32;
    const int fr = lane & 15, ko = lane >> 4;

    f32x4 acc[2][2] = {};

    for (int icc = 0; icc < 8; icc++) {
        __syncthreads();
        // stage input halo tile 6x18 px, 32 ic (swizzled chunk: ch ^ ((s>>1)&3))
        #pragma unroll
        for (int id = tid; id < 432; id += 256) {
            int pxi = id >> 2, ch = id & 3;
            int r = pxi / 18, s = pxi - r * 18;
            int gy = y0 - 1 + r, gx = x0 - 1 + s;
            us8 v = {};
            if (gy >= 0 && gy < 64 && gx >= 0 && gx < 64)
                v = *(const us8*)&inb[((size_t)(gy * 64 + gx) << 8) + (icc << 5) + (ch << 3)];
            *(us8*)&sIn[(pxi << 5) + ((ch ^ ((s >> 1) & 3)) << 3)] = v;
        }
        // stage weights (linear copy; swizzle baked into wcb)
        const unsigned short* wsrc = wcb + (((size_t)icc * 256 + oc0) * 9 << 5);
        #pragma unroll
        for (int id = tid; id < 2304; id += 256)
            *(us8*)&sW[id << 3] = *(const us8*)&wsrc[id << 3];
        __syncthreads();

        #pragma unroll
        for (int tap = 0; tap < 9; tap++) {
            const int ky = tap / 3, kx = tap - ky * 3;
            bf16x8 a[2], b[2];
            #pragma unroll
            for (int i = 0; i < 2; i++) {
                int px = wm + i * 16 + fr;
                int r = (px >> 4) + ky;
                int s = (px & 15) + kx;
                a[i] = *(const bf16x8*)&sIn[(((r * 18 + s)) << 5) + ((ko ^ ((s >> 1) & 3)) << 3)];
            }
            #pragma unroll
            for (int j = 0; j < 2; j++) {
                int oc = wn + j * 16 + fr;
                b[j] = *(const bf16x8*)&sW[(((oc * 9) + tap) << 5) + ((ko ^ ((oc >> 1) & 3)) << 3)];
            }
            #pragma unroll
            for (int i = 0; i < 2; i++)
                #pragma unroll
                for (int j = 0; j < 2; j++)
                    acc[i][j] = __builtin_amdgcn_mfma_f32_16x16x32_bf16(a[i], b[j], acc[i][j], 0, 0, 0);
        }
    }

    // epilogue: transpose through LDS for coalesced NCHW stores
    __syncthreads();
    #pragma unroll
    for (int i = 0; i < 2; i++)
        #pragma unroll
        for (int j = 0; j < 2; j++) {
            int oc = wn + j * 16 + fr;
            int pxb = wm + i * 16 + ko * 4;
            *(f32x4*)&sO[oc * 68 + pxb] = acc[i][j];
        }
    __syncthreads();
    {
        int oc_r = tid >> 2, yy = tid & 3;
        float* dst = &out[(size_t)(oc0 + oc_r) * 4096 + (y0 + yy) * 64 + x0];
        const float* srcl = &sO[oc_r * 68 + yy * 16];
        #pragma unroll
        for (int q = 0; q < 4; q++)
            *(float4*)&dst[q * 4] = *(const float4*)&srcl[q * 4];
    }
}

// ---------------- groupnorm stats ----------------
__global__ __launch_bounds__(256) void gnstats_k(const float* __restrict__ x, float* __restrict__ st)
{
    int g = blockIdx.x;
    const float* p = x + (size_t)g * 8 * 4096;
    float s = 0.f, ss = 0.f;
    for (int i = threadIdx.x * 4; i < 32768; i += 1024) {
        float4 v = ld4(&p[i]);
        s  += v.x + v.y + v.z + v.w;
        ss += v.x * v.x + v.y * v.y + v.z * v.z + v.w * v.w;
    }
    #pragma unroll
    for (int o = 32; o > 0; o >>= 1) {
        s  += __shfl_xor(s, o, 64);
        ss += __shfl_xor(ss, o, 64);
    }
    __shared__ float rs[4], rss[4];
    int wid = threadIdx.x >> 6;
    if ((threadIdx.x & 63) == 0) { rs[wid] = s; rss[wid] = ss; }
    __syncthreads();
    if (threadIdx.x == 0) {
        float S = rs[0] + rs[1] + rs[2] + rs[3];
        float SS = rss[0] + rss[1] + rss[2] + rss[3];
        float m = S * (1.f / 32768.f);
        float var = SS * (1.f / 32768.f) - m * m;
        st[g * 2] = m;
        st[g * 2 + 1] = rsqrtf(var + 1e-5f);
    }
}

// ---------------- groupnorm apply + relu -> bf16 NHWC ----------------
__global__ void gnapply_b_k(const float* __restrict__ x, const float* __restrict__ st,
                            const float* __restrict__ w, const float* __restrict__ b,
                            unsigned short* __restrict__ o)
{
    int i = blockIdx.x * blockDim.x + threadIdx.x;
    if (i >= 262144) return;
    int c = i >> 10;
    int g = c >> 3;
    int px0 = (i & 1023) << 2;
    float m = st[g * 2], rs = st[g * 2 + 1];
    float sw = w[c], sb = b[c];
    float4 v = ld4(&x[(size_t)i << 2]);
    float r0 = fmaxf((v.x - m) * rs * sw + sb, 0.f);
    float r1 = fmaxf((v.y - m) * rs * sw + sb, 0.f);
    float r2 = fmaxf((v.z - m) * rs * sw + sb, 0.f);
    float r3 = fmaxf((v.w - m) * rs * sw + sb, 0.f);
    o[(size_t)(px0 + 0) * 256 + c] = f2bf(r0);
    o[(size_t)(px0 + 1) * 256 + c] = f2bf(r1);
    o[(size_t)(px0 + 2) * 256 + c] = f2bf(r2);
    o[(size_t)(px0 + 3) * 256 + c] = f2bf(r3);
}

// ---------------- groupnorm apply + relu -> f32 NCHW ----------------
__global__ void gnapply_f_k(const float* __restrict__ x, const float* __restrict__ st,
                            const float* __restrict__ w, const float* __restrict__ b,
                            float* __restrict__ o)
{
    int i = blockIdx.x * blockDim.x + threadIdx.x;
    if (i >= 262144) return;
    int c = i >> 10;
    int g = c >> 3;
    float m = st[g * 2], rs = st[g * 2 + 1];
    float sw = w[c], sb = b[c];
    float4 v = ld4(&x[(size_t)i << 2]);
    float4 r;
    r.x = fmaxf((v.x - m) * rs * sw + sb, 0.f);
    r.y = fmaxf((v.y - m) * rs * sw + sb, 0.f);
    r.z = fmaxf((v.z - m) * rs * sw + sb, 0.f);
    r.w = fmaxf((v.w - m) * rs * sw + sb, 0.f);
    *(float4*)&o[(size_t)i << 2] = r;
}

// ---------------- host launcher ----------------
extern "C" void kernel_launch(void* const* d_in, const int* in_sizes, int n_in,
                              void* d_out, int out_size, void* d_ws, size_t ws_size,
                              hipStream_t stream)
{
    (void)in_sizes; (void)n_in; (void)out_size; (void)ws_size;
    const float* feat0 = (const float*)d_in[0];
    const float* feat1 = (const float*)d_in[1];
    const float* feat2 = (const float*)d_in[2];
    const float* in0_w = (const float*)d_in[3];
    const float* in0_b = (const float*)d_in[4];
    const float* in1_w = (const float*)d_in[5];
    const float* in1_b = (const float*)d_in[6];
    const float* in2_w = (const float*)d_in[7];
    const float* in2_b = (const float*)d_in[8];
    const float* off_w = (const float*)d_in[9];
    const float* off_b = (const float*)d_in[10];
    const float* aw_w  = (const float*)d_in[11];
    const float* aw_b  = (const float*)d_in[12];
    const float* vp_w  = (const float*)d_in[13];
    const float* vp_b  = (const float*)d_in[14];
    const float* op_w  = (const float*)d_in[15];
    const float* op_b  = (const float*)d_in[16];
    const float* n1_w  = (const float*)d_in[17];
    const float* n1_b  = (const float*)d_in[18];
    const float* ff1_w = (const float*)d_in[19];
    const float* ff1_b = (const float*)d_in[20];
    const float* ff2_w = (const float*)d_in[21];
    const float* ff2_b = (const float*)d_in[22];
    const float* n2_w  = (const float*)d_in[23];
    const float* n2_b  = (const float*)d_in[24];
    const float* fn_w  = (const float*)d_in[25];
    const float* fn_b  = (const float*)d_in[26];
    const float* lat_w = (const float*)d_in[27];
    const float* lat_b = (const float*)d_in[28];
    const float* out_w = (const float*)d_in[29];
    const float* gnw   = (const float*)d_in[30];
    const float* gnb   = (const float*)d_in[31];
    float* out = (float*)d_out;

    // ---- workspace (~59 MB; 69.6 MB proven safe) ----
    float* ws     = (float*)d_ws;
    float* src    = ws;                 // 1376256
    float* pos    = src  + 1376256;     // 1376256 (reused as conv out `pong` after encoder)
    float* tmp    = pos  + 1376256;     // 1376256
    float* valbuf = tmp  + 1376256;     // 1376256 (valb bf16 | latb bf16)
    float* oab    = valbuf + 1376256;   // 1548288 (off 192 | aw 96 per token)
    float* stats  = oab  + 1548288;     // 64
    float* boa    = stats + 64;         // 1728
    float* pong   = pos;                // alias

    unsigned short* valb = (unsigned short*)valbuf;            // 1376256 bf16
    unsigned short* latb = (unsigned short*)(valbuf + 688128); // 1048576 bf16

    unsigned short* ub = (unsigned short*)(boa + 1728);
    unsigned short* srcb  = ub; ub += 1376256;
    unsigned short* qbb   = ub; ub += 1376256;  // pingb alias after encoder
    unsigned short* msdb  = ub; ub += 1376256;
    unsigned short* ffhb  = ub; ub += 5505024;  // hosts fT0/1/2 during setup
    unsigned short* w_oa  = ub; ub += 442368;
    unsigned short* w_vp  = ub; ub += 393216;
    unsigned short* w_op  = ub; ub += 393216;
    unsigned short* w_ff1 = ub; ub += 1572864;
    unsigned short* w_ff2 = ub; ub += 1572864;
    unsigned short* w_in0 = ub; ub += 65536;
    unsigned short* w_in1 = ub; ub += 131072;
    unsigned short* w_in2 = ub; ub += 262144;
    unsigned short* w_lat = ub; ub += 65536;
    unsigned short* wcb   = ub; ub += 1769472;

    unsigned short* fT0 = ffhb;
    unsigned short* fT1 = ffhb + 1048576;
    unsigned short* fT2 = ffhb + 1572864;
    unsigned short* pingb = qbb;  // NHWC bf16 conv input (qbb dead after encoder)

    // ---- setup ----
    pack_oa_k<<<1728, 256, 0, stream>>>(off_w, off_b, aw_w, aw_b, w_oa, boa);
    wconv_k<<<6912, 256, 0, stream>>>(out_w, wcb);
    cvt4_k<<<384, 256, 0, stream>>>(vp_w,  w_vp,  98304);
    cvt4_k<<<384, 256, 0, stream>>>(op_w,  w_op,  98304);
    cvt4_k<<<1536,256, 0, stream>>>(ff1_w, w_ff1, 393216);
    cvt4_k<<<1536,256, 0, stream>>>(ff2_w, w_ff2, 393216);
    cvt4_k<<<64,  256, 0, stream>>>(in0_w, w_in0, 16384);
    cvt4_k<<<128, 256, 0, stream>>>(in1_w, w_in1, 32768);
    cvt4_k<<<256, 256, 0, stream>>>(in2_w, w_in2, 65536);
    cvt4_k<<<64,  256, 0, stream>>>(lat_w, w_lat, 16384);
    cvtT_k<<<dim3(128, 8), dim3(32, 8), 0, stream>>>(feat0, fT0, 256, 4096);
    cvtT_k<<<dim3(32, 16), dim3(32, 8), 0, stream>>>(feat1, fT1, 512, 1024);
    cvtT_k<<<dim3(8, 32),  dim3(32, 8), 0, stream>>>(feat2, fT2, 1024, 256);
    posenc_k<<<2688, 256, 0, stream>>>(pos);

    // ---- input projections ----
    bgemm_k<2,false><<<dim3(4,64), 256, 0, stream>>>(fT0, w_in0, in0_b, src,            srcb,            4096, 256, 256);
    bgemm_k<2,false><<<dim3(4,16), 256, 0, stream>>>(fT1, w_in1, in1_b, src + 4096*256, srcb + 4096*256, 1024, 256, 512);
    bgemm_k<2,false><<<dim3(4,4),  256, 0, stream>>>(fT2, w_in2, in2_b, src + 5120*256, srcb + 5120*256, 256,  256, 1024);

    // ---- encoder layers ----
    for (int i = 0; i < 6; i++) {
        addb_k<<<1344, 256, 0, stream>>>(src, pos, qbb, 344064);
        bgemm_k<0,false><<<dim3(5,84), 256, 0, stream>>>(qbb,  w_oa + i*73728, boa + i*288, oab, nullptr, 5376, 288, 256);
        softmax12_k<<<168, 256, 0, stream>>>(oab);
        bgemm_k<1,false><<<dim3(4,84), 256, 0, stream>>>(srcb, w_vp + i*65536, vp_b + i*256, nullptr, valb, 5376, 256, 256);
        msdef_k<<<672, 256, 0, stream>>>(valb, oab, msdb);
        bgemm_k<0,false><<<dim3(4,84), 256, 0, stream>>>(msdb, w_op + i*65536, op_b + i*256, tmp, nullptr, 5376, 256, 256);
        ln_k<true><<<1344, 256, 0, stream>>>(src, tmp, n1_w + i*256, n1_b + i*256, srcb);
        bgemm_k<1,true ><<<dim3(16,84),256, 0, stream>>>(srcb, w_ff1 + i*262144, ff1_b + i*1024, nullptr, ffhb, 5376, 1024, 256);
        bgemm_k<0,false><<<dim3(4,84), 256, 0, stream>>>(ffhb, w_ff2 + i*262144, ff2_b + i*256, tmp, nullptr, 5376, 256, 1024);
        ln_k<true><<<1344, 256, 0, stream>>>(src, tmp, n2_w + i*256, n2_b + i*256, srcb);
    }
    ln_k<false><<<1344, 256, 0, stream>>>(src, nullptr, fn_w, fn_b, srcb);

    // ---- mems -> d_out (NCHW) ----
    tr_k<<<dim3(128,8), dim3(32,8), 0, stream>>>(src,           out + 1048576, 4096);
    tr_k<<<dim3(32,8),  dim3(32,8), 0, stream>>>(src + 1048576, out + 2097152, 1024);
    tr_k<<<dim3(8,8),   dim3(32,8), 0, stream>>>(src + 1310720, out + 2359296, 256);

    // ---- lateral 1x1 -> bf16 NHWC directly ----
    bgemm_k<1,false><<<dim3(4,64), 256, 0, stream>>>(srcb, w_lat, lat_b, nullptr, latb, 4096, 256, 256);

    // ---- 3x (conv3x3 MFMA -> groupnorm -> relu) ----
    conv3b_k<<<dim3(64,4), 256, 0, stream>>>(latb, wcb, pong);
    gnstats_k<<<32, 256, 0, stream>>>(pong, stats);
    gnapply_b_k<<<1024, 256, 0, stream>>>(pong, stats, gnw, gnb, pingb);

    conv3b_k<<<dim3(64,4), 256, 0, stream>>>(pingb, wcb + 589824, pong);
    gnstats_k<<<32, 256, 0, stream>>>(pong, stats);
    gnapply_b_k<<<1024, 256, 0, stream>>>(pong, stats, gnw + 256, gnb + 256, pingb);

    conv3b_k<<<dim3(64,4), 256, 0, stream>>>(pingb, wcb + 1179648, pong);
    gnstats_k<<<32, 256, 0, stream>>>(pong, stats);
    gnapply_f_k<<<1024, 256, 0, stream>>>(pong, stats, gnw + 512, gnb + 512, out);
}

// Round 5
// 659.110 us; speedup vs baseline: 3.7892x; 1.1072x over previous
//
#include <hip/hip_runtime.h>
#include <math.h>

#define LTOT 5376

typedef __attribute__((ext_vector_type(8))) __bf16 bf16x8;
typedef __attribute__((ext_vector_type(4))) float f32x4;
typedef __attribute__((ext_vector_type(8))) unsigned short us8;
typedef __attribute__((ext_vector_type(4))) unsigned short us4;

static __device__ __forceinline__ float4 ld4(const float* p) { return *(const float4*)p; }

static __device__ __forceinline__ unsigned short f2bf(float f) {
    unsigned int u = __float_as_uint(f);
    return (unsigned short)((u + 0x7fffu + ((u >> 16) & 1u)) >> 16);
}
static __device__ __forceinline__ float bf2f(unsigned short s) {
    return __uint_as_float(((unsigned int)s) << 16);
}

// async global->LDS, 16B per lane; lds base must be wave-uniform (HW adds lane*16)
static __device__ __forceinline__ void gl16(const unsigned short* g, unsigned short* l) {
    __builtin_amdgcn_global_load_lds(
        (const __attribute__((address_space(1))) unsigned int*)g,
        (__attribute__((address_space(3))) unsigned int*)l, 16, 0, 0);
}

// ---------------- bf16 MFMA GEMM, 2-phase gload_lds pipeline ----------------
// C(M,N) = A(M,K)bf16 @ B(N,K)bf16^T + bias(N)
// 64x64 tile, BK=64, dbuf LDS; 256 thr = 4 waves (2x2), wave 32x32.
// LDS row = 64 shorts (128B) = 8 chunks of 16B; global chunk c stored at slot c^(row&7).
// OMODE: 0 = f32 out, 1 = bf16 out, 2 = both
template<int OMODE, bool RELU>
__global__ __launch_bounds__(256) void bgemm_k(
    const unsigned short* __restrict__ A,
    const unsigned short* __restrict__ B,
    const float* __restrict__ bias,
    float* __restrict__ C1,
    unsigned short* __restrict__ C2,
    int M, int N, int K)
{
    __shared__ unsigned short As[2][64 * 64];
    __shared__ unsigned short Bs[2][64 * 64];
    const int tid  = threadIdx.x;
    const int m0   = blockIdx.y * 64;
    const int n0   = blockIdx.x * 64;
    const int wave = tid >> 6;
    const int lane = tid & 63;
    const int wm   = (wave >> 1) * 32;
    const int wn   = (wave & 1) * 32;
    const int fr   = lane & 15;
    const int ko   = lane >> 4;

    // two staging chunks per thread: q0 = tid, q1 = tid + 256 (of 512 chunks)
    const int q0 = tid, q1 = tid + 256;
    const int r0 = q0 >> 3, c0v = (q0 & 7) ^ (r0 & 7);
    const int r1 = q1 >> 3, c1v = (q1 & 7) ^ (r1 & 7);
    const unsigned short* a0 = A + (size_t)(m0 + r0) * K + (c0v << 3);
    const unsigned short* a1 = A + (size_t)(m0 + r1) * K + (c1v << 3);
    int bn0 = n0 + r0; if (bn0 > N - 1) bn0 = N - 1;
    int bn1 = n0 + r1; if (bn1 > N - 1) bn1 = N - 1;
    const unsigned short* b0 = B + (size_t)bn0 * K + (c0v << 3);
    const unsigned short* b1 = B + (size_t)bn1 * K + (c1v << 3);
    const int wb = wave << 9;  // wave-uniform lds base (shorts) within a round

    f32x4 acc[2][2] = {};

    auto stage = [&](int buf, int kof) {
        gl16(a0 + kof, &As[buf][wb]);
        gl16(a1 + kof, &As[buf][2048 + wb]);
        gl16(b0 + kof, &Bs[buf][wb]);
        gl16(b1 + kof, &Bs[buf][2048 + wb]);
    };

    const int nt = K >> 6;
    stage(0, 0);
    __syncthreads();
    int buf = 0;
    for (int t = 0; t < nt; t++) {
        if (t + 1 < nt) stage(buf ^ 1, (t + 1) << 6);
        #pragma unroll
        for (int sub = 0; sub < 2; sub++) {
            bf16x8 af[2], bfr[2];
            const int kk = (sub << 2) + ko;
            #pragma unroll
            for (int i = 0; i < 2; i++) {
                int r = wm + i * 16 + fr;
                af[i] = *(const bf16x8*)&As[buf][(r << 6) + ((kk ^ (r & 7)) << 3)];
                int c = wn + i * 16 + fr;
                bfr[i] = *(const bf16x8*)&Bs[buf][(c << 6) + ((kk ^ (c & 7)) << 3)];
            }
            #pragma unroll
            for (int i = 0; i < 2; i++)
                #pragma unroll
                for (int j = 0; j < 2; j++)
                    acc[i][j] = __builtin_amdgcn_mfma_f32_16x16x32_bf16(af[i], bfr[j], acc[i][j], 0, 0, 0);
        }
        __syncthreads();
        buf ^= 1;
    }

    #pragma unroll
    for (int j = 0; j < 2; j++) {
        int col = n0 + wn + j * 16 + fr;
        if (col >= N) continue;
        float cb = bias[col];
        #pragma unroll
        for (int i = 0; i < 2; i++) {
            #pragma unroll
            for (int r = 0; r < 4; r++) {
                int row = m0 + wm + i * 16 + ko * 4 + r;
                float v = acc[i][j][r] + cb;
                if (RELU) v = fmaxf(v, 0.f);
                size_t off = (size_t)row * N + col;
                if (OMODE == 0) C1[off] = v;
                else if (OMODE == 1) C2[off] = f2bf(v);
                else { C1[off] = v; C2[off] = f2bf(v); }
            }
        }
    }
}

// ---------------- fused fp32 -> bf16 convert for all plain weights ----------------
// dest is one contiguous bf16 run: [vp | op | ff1 | ff2 | in0 | in1 | in2 | lat]
__global__ void cvtall_k(const float* __restrict__ s0, const float* __restrict__ s1,
                         const float* __restrict__ s2, const float* __restrict__ s3,
                         const float* __restrict__ s4, const float* __restrict__ s5,
                         const float* __restrict__ s6, const float* __restrict__ s7,
                         unsigned short* __restrict__ d)
{
    int i = blockIdx.x * blockDim.x + threadIdx.x;  // quad index
    if (i >= 1114112) return;
    const float* s; int off;
    if      (i <   98304) { s = s0; off = 0; }
    else if (i <  196608) { s = s1; off = 98304; }
    else if (i <  589824) { s = s2; off = 196608; }
    else if (i <  983040) { s = s3; off = 589824; }
    else if (i <  999424) { s = s4; off = 983040; }
    else if (i < 1032192) { s = s5; off = 999424; }
    else if (i < 1097728) { s = s6; off = 1032192; }
    else                  { s = s7; off = 1097728; }
    float4 v = ld4(&s[(size_t)(i - off) << 2]);
    us4 r = { f2bf(v.x), f2bf(v.y), f2bf(v.z), f2bf(v.w) };
    *(us4*)&d[(size_t)i << 2] = r;
}

// ---------------- (Ci,P) fp32 -> (P,Ci) bf16 transpose ----------------
__global__ void cvtT_k(const float* __restrict__ src, unsigned short* __restrict__ dst, int Ci, int P)
{
    __shared__ float t[32][33];
    int c0 = blockIdx.y * 32, p0 = blockIdx.x * 32;
    int x = threadIdx.x, y = threadIdx.y;
    for (int i = y; i < 32; i += 8)
        t[i][x] = src[(size_t)(c0 + i) * P + p0 + x];
    __syncthreads();
    for (int i = y; i < 32; i += 8)
        dst[(size_t)(p0 + i) * Ci + c0 + x] = f2bf(t[x][i]);
}

// ---------------- pack off|aw weights+bias per layer ----------------
__global__ void pack_oa_k(const float* __restrict__ off_w, const float* __restrict__ off_b,
                          const float* __restrict__ aw_w,  const float* __restrict__ aw_b,
                          unsigned short* __restrict__ w_oa, float* __restrict__ b_oa)
{
    int idx = blockIdx.x * blockDim.x + threadIdx.x;
    if (idx >= 6 * 288 * 256) return;
    int i = idx / 73728;
    int r = idx - i * 73728;
    int n = r >> 8;
    int k = r & 255;
    float v = (n < 192) ? off_w[((size_t)i * 192 + n) * 256 + k]
                        : aw_w[((size_t)i * 96 + (n - 192)) * 256 + k];
    w_oa[idx] = f2bf(v);
    if (k == 0)
        b_oa[i * 288 + n] = (n < 192) ? off_b[i * 192 + n] : aw_b[i * 96 + (n - 192)];
}

// ---------------- conv weight repack ----------------
__global__ void wconv_k(const float* __restrict__ out_w, unsigned short* __restrict__ wcb)
{
    int idx = blockIdx.x * blockDim.x + threadIdx.x;
    if (idx >= 3 * 589824) return;
    int c   = idx / 589824;
    int r   = idx - c * 589824;
    int icc = r / 73728;
    int r2  = r - icc * 73728;
    int oc  = r2 / 288;
    int r3  = r2 - oc * 288;
    int tap = r3 >> 5;
    int sl  = r3 & 31;
    int ic  = icc * 32 + (((sl >> 3) ^ ((oc >> 1) & 3)) << 3) + (sl & 7);
    wcb[idx] = f2bf(out_w[(((size_t)(c * 256 + oc)) * 256 + ic) * 9 + tap]);
}

// ---------------- sine positional encoding ----------------
__global__ void posenc_k(float* __restrict__ pos)
{
    int idx = blockIdx.x * blockDim.x + threadIdx.x;
    if (idx >= LTOT * 128) return;
    int l = idx >> 7;
    int pr = idx & 127;
    int half = pr >> 6;
    int j = pr & 63;
    int HW, sh, p;
    if (l < 4096)      { HW = 64; sh = 6; p = l; }
    else if (l < 5120) { HW = 32; sh = 5; p = l - 4096; }
    else               { HW = 16; sh = 4; p = l - 5120; }
    int y = p >> sh;
    int x = p & (HW - 1);
    float T = powf(10000.f, (float)j * (1.f / 64.f));
    float coord = (half == 0) ? (float)(y + 1) : (float)(x + 1);
    float v = coord / ((float)HW + 1e-6f) * 6.283185307179586f;
    float arg = v / T;
    size_t base = (size_t)l * 256 + half * 128 + (j << 1);
    pos[base]     = sinf(arg);
    pos[base + 1] = cosf(arg);
}

// ---------------- q = src + pos -> bf16 (layer 0 only) ----------------
__global__ void addb_k(const float* __restrict__ a, const float* __restrict__ b,
                       unsigned short* __restrict__ o, int n4)
{
    int i = blockIdx.x * blockDim.x + threadIdx.x;
    if (i >= n4) return;
    float4 x = ld4(&a[(size_t)i << 2]);
    float4 y = ld4(&b[(size_t)i << 2]);
    us4 r = { f2bf(x.x + y.x), f2bf(x.y + y.y), f2bf(x.z + y.z), f2bf(x.w + y.w) };
    *(us4*)&o[(size_t)i << 2] = r;
}

// ---------------- multi-scale deformable sampling, softmax fused ----------------
// valb: (L,256) bf16; oab: (L,288) f32 raw [off 192 | aw-scores 96]; out bf16
// block = 8 positions x 32 thr; thread: 1 head x 8 channels
__global__ __launch_bounds__(256) void msdef_k(
    const unsigned short* __restrict__ valb, const float* __restrict__ oab,
    unsigned short* __restrict__ out)
{
    __shared__ float sw[8 * 288];
    const int tid = threadIdx.x;
    const int bl = blockIdx.x;
    #pragma unroll
    for (int id = tid; id < 576; id += 256)
        ((float4*)sw)[id] = ((const float4*)(oab + (size_t)bl * 2304))[id];
    __syncthreads();

    const int p = tid >> 5;
    const int t = tid & 31;
    const int l = bl * 8 + p;
    const int h = t >> 2;
    const int co = (t & 3) << 3;
    const float* mo = sw + p * 288;

    // softmax over the 12 raw scores of this head (redundant x4 threads, cheap)
    float aw_r[12];
    {
        const float* sc = mo + 192 + h * 12;
        float mx = -1e30f;
        #pragma unroll
        for (int j = 0; j < 12; j++) { aw_r[j] = sc[j]; mx = fmaxf(mx, aw_r[j]); }
        float su = 0.f;
        #pragma unroll
        for (int j = 0; j < 12; j++) { aw_r[j] = expf(aw_r[j] - mx); su += aw_r[j]; }
        float inv = 1.f / su;
        #pragma unroll
        for (int j = 0; j < 12; j++) aw_r[j] *= inv;
    }

    float rx, ry;
    {
        int HW, sh, q;
        if (l < 4096)      { HW = 64; sh = 6; q = l; }
        else if (l < 5120) { HW = 32; sh = 5; q = l - 4096; }
        else               { HW = 16; sh = 4; q = l - 5120; }
        int y = q >> sh;
        int x = q & (HW - 1);
        rx = (x + 0.5f) / (float)HW;
        ry = (y + 0.5f) / (float)HW;
    }

    const int starts[3] = {0, 4096, 5120};
    const int dims[3]   = {64, 32, 16};
    float acc[8] = {};
    #pragma unroll
    for (int s = 0; s < 3; s++) {
        const int D = dims[s];
        const int st = starts[s];
        #pragma unroll
        for (int pt = 0; pt < 4; pt++) {
            float a  = aw_r[(s << 2) + pt];
            float px = rx * D + mo[h * 24 + (s << 3) + (pt << 1)]     - 0.5f;
            float py = ry * D + mo[h * 24 + (s << 3) + (pt << 1) + 1] - 0.5f;
            float x0f = floorf(px), y0f = floorf(py);
            float lx = px - x0f, ly = py - y0f;
            int x0 = (int)x0f, y0 = (int)y0f;
            float w00 = a * (1.f - lx) * (1.f - ly);
            float w10 = a * lx * (1.f - ly);
            float w01 = a * (1.f - lx) * ly;
            float w11 = a * lx * ly;
            #pragma unroll
            for (int cy = 0; cy < 2; cy++) {
                int yi = y0 + cy;
                if (yi < 0 || yi >= D) continue;
                #pragma unroll
                for (int cx = 0; cx < 2; cx++) {
                    int xi = x0 + cx;
                    if (xi < 0 || xi >= D) continue;
                    float w = cy ? (cx ? w11 : w01) : (cx ? w10 : w00);
                    us8 v = *(const us8*)&valb[((size_t)(st + yi * D + xi) << 8) + (h << 5) + co];
                    #pragma unroll
                    for (int e = 0; e < 8; e++)
                        acc[e] = fmaf(w, bf2f(v[e]), acc[e]);
                }
            }
        }
    }
    us8 r;
    #pragma unroll
    for (int e = 0; e < 8; e++) r[e] = f2bf(acc[e]);
    *(us8*)&out[((size_t)l << 8) + (h << 5) + co] = r;
}

// ---------------- layernorm (+residual), in-place fp32 + bf16 copy (+ q=out+pos) ----------------
template<bool HAS_ADD, bool HAS_POS>
__global__ __launch_bounds__(256) void ln_k(float* __restrict__ src, const float* __restrict__ add,
                                            const float* __restrict__ w, const float* __restrict__ b,
                                            unsigned short* __restrict__ outb,
                                            const float* __restrict__ posf,
                                            unsigned short* __restrict__ qbout)
{
    int row = blockIdx.x * 4 + (threadIdx.x >> 6);
    int lane = threadIdx.x & 63;
    size_t base = (size_t)row * 256 + (lane << 2);
    float4 x = ld4(&src[base]);
    if (HAS_ADD) {
        float4 a = ld4(&add[base]);
        x.x += a.x; x.y += a.y; x.z += a.z; x.w += a.w;
    }
    float s = x.x + x.y + x.z + x.w;
    #pragma unroll
    for (int o = 32; o > 0; o >>= 1) s += __shfl_xor(s, o, 64);
    float m = s * (1.f / 256.f);
    float d0 = x.x - m, d1 = x.y - m, d2 = x.z - m, d3 = x.w - m;
    float v = d0 * d0 + d1 * d1 + d2 * d2 + d3 * d3;
    #pragma unroll
    for (int o = 32; o > 0; o >>= 1) v += __shfl_xor(v, o, 64);
    float rs = rsqrtf(v * (1.f / 256.f) + 1e-5f);
    float4 wv = ld4(&w[lane << 2]);
    float4 bv = ld4(&b[lane << 2]);
    float4 o4;
    o4.x = d0 * rs * wv.x + bv.x;
    o4.y = d1 * rs * wv.y + bv.y;
    o4.z = d2 * rs * wv.z + bv.z;
    o4.w = d3 * rs * wv.w + bv.w;
    *(float4*)&src[base] = o4;
    us4 r = { f2bf(o4.x), f2bf(o4.y), f2bf(o4.z), f2bf(o4.w) };
    *(us4*)&outb[base] = r;
    if (HAS_POS) {
        float4 p4 = ld4(&posf[base]);
        us4 q = { f2bf(o4.x + p4.x), f2bf(o4.y + p4.y), f2bf(o4.z + p4.z), f2bf(o4.w + p4.w) };
        *(us4*)&qbout[base] = q;
    }
}

// ---------------- (HW,256) -> (256,HW) transpose (fp32) ----------------
__global__ void tr_k(const float* __restrict__ src, float* __restrict__ dst, int HW)
{
    __shared__ float t[32][33];
    int p0 = blockIdx.x * 32, c0 = blockIdx.y * 32;
    int x = threadIdx.x, y = threadIdx.y;
    for (int i = y; i < 32; i += 8)
        t[i][x] = src[(size_t)(p0 + i) * 256 + c0 + x];
    __syncthreads();
    for (int i = y; i < 32; i += 8)
        dst[(size_t)(c0 + i) * HW + p0 + x] = t[x][i];
}

// ---------------- 3x3 conv via bf16 MFMA implicit GEMM ----------------
__global__ __launch_bounds__(256) void conv3b_k(const unsigned short* __restrict__ inb,
                                                const unsigned short* __restrict__ wcb,
                                                float* __restrict__ out)
{
    __shared__ __align__(16) unsigned char smem[43776];
    unsigned short* sIn = (unsigned short*)smem;
    unsigned short* sW  = (unsigned short*)(smem + 6912);
    float* sO = (float*)smem;

    const int tid = threadIdx.x;
    const int mb = blockIdx.x;
    const int y0 = (mb >> 2) << 2;
    const int x0 = (mb & 3) << 4;
    const int oc0 = blockIdx.y << 6;
    const int wave = tid >> 6, lane = tid & 63;
    const int wm = (wave >> 1) * 32, wn = (wave & 1) * 32;
    const int fr = lane & 15, ko = lane >> 4;

    f32x4 acc[2][2] = {};

    for (int icc = 0; icc < 8; icc++) {
        __syncthreads();
        #pragma unroll
        for (int id = tid; id < 432; id += 256) {
            int pxi = id >> 2, ch = id & 3;
            int r = pxi / 18, s = pxi - r * 18;
            int gy = y0 - 1 + r, gx = x0 - 1 + s;
            us8 v = {};
            if (gy >= 0 && gy < 64 && gx >= 0 && gx < 64)
                v = *(const us8*)&inb[((size_t)(gy * 64 + gx) << 8) + (icc << 5) + (ch << 3)];
            *(us8*)&sIn[(pxi << 5) + ((ch ^ ((s >> 1) & 3)) << 3)] = v;
        }
        const unsigned short* wsrc = wcb + (((size_t)icc * 256 + oc0) * 9 << 5);
        #pragma unroll
        for (int id = tid; id < 2304; id += 256)
            *(us8*)&sW[id << 3] = *(const us8*)&wsrc[id << 3];
        __syncthreads();

        #pragma unroll
        for (int tap = 0; tap < 9; tap++) {
            const int ky = tap / 3, kx = tap - ky * 3;
            bf16x8 a[2], b[2];
            #pragma unroll
            for (int i = 0; i < 2; i++) {
                int px = wm + i * 16 + fr;
                int r = (px >> 4) + ky;
                int s = (px & 15) + kx;
                a[i] = *(const bf16x8*)&sIn[(((r * 18 + s)) << 5) + ((ko ^ ((s >> 1) & 3)) << 3)];
            }
            #pragma unroll
            for (int j = 0; j < 2; j++) {
                int oc = wn + j * 16 + fr;
                b[j] = *(const bf16x8*)&sW[(((oc * 9) + tap) << 5) + ((ko ^ ((oc >> 1) & 3)) << 3)];
            }
            #pragma unroll
            for (int i = 0; i < 2; i++)
                #pragma unroll
                for (int j = 0; j < 2; j++)
                    acc[i][j] = __builtin_amdgcn_mfma_f32_16x16x32_bf16(a[i], b[j], acc[i][j], 0, 0, 0);
        }
    }

    __syncthreads();
    #pragma unroll
    for (int i = 0; i < 2; i++)
        #pragma unroll
        for (int j = 0; j < 2; j++) {
            int oc = wn + j * 16 + fr;
            int pxb = wm + i * 16 + ko * 4;
            *(f32x4*)&sO[oc * 68 + pxb] = acc[i][j];
        }
    __syncthreads();
    {
        int oc_r = tid >> 2, yy = tid & 3;
        float* dst = &out[(size_t)(oc0 + oc_r) * 4096 + (y0 + yy) * 64 + x0];
        const float* srcl = &sO[oc_r * 68 + yy * 16];
        #pragma unroll
        for (int q = 0; q < 4; q++)
            *(float4*)&dst[q * 4] = *(const float4*)&srcl[q * 4];
    }
}

// ---------------- groupnorm stats ----------------
__global__ __launch_bounds__(256) void gnstats_k(const float* __restrict__ x, float* __restrict__ st)
{
    int g = blockIdx.x;
    const float* p = x + (size_t)g * 8 * 4096;
    float s = 0.f, ss = 0.f;
    for (int i = threadIdx.x * 4; i < 32768; i += 1024) {
        float4 v = ld4(&p[i]);
        s  += v.x + v.y + v.z + v.w;
        ss += v.x * v.x + v.y * v.y + v.z * v.z + v.w * v.w;
    }
    #pragma unroll
    for (int o = 32; o > 0; o >>= 1) {
        s  += __shfl_xor(s, o, 64);
        ss += __shfl_xor(ss, o, 64);
    }
    __shared__ float rs[4], rss[4];
    int wid = threadIdx.x >> 6;
    if ((threadIdx.x & 63) == 0) { rs[wid] = s; rss[wid] = ss; }
    __syncthreads();
    if (threadIdx.x == 0) {
        float S = rs[0] + rs[1] + rs[2] + rs[3];
        float SS = rss[0] + rss[1] + rss[2] + rss[3];
        float m = S * (1.f / 32768.f);
        float var = SS * (1.f / 32768.f) - m * m;
        st[g * 2] = m;
        st[g * 2 + 1] = rsqrtf(var + 1e-5f);
    }
}

// ---------------- groupnorm apply + relu -> bf16 NHWC ----------------
__global__ void gnapply_b_k(const float* __restrict__ x, const float* __restrict__ st,
                            const float* __restrict__ w, const float* __restrict__ b,
                            unsigned short* __restrict__ o)
{
    int i = blockIdx.x * blockDim.x + threadIdx.x;
    if (i >= 262144) return;
    int c = i >> 10;
    int g = c >> 3;
    int px0 = (i & 1023) << 2;
    float m = st[g * 2], rs = st[g * 2 + 1];
    float sw = w[c], sb = b[c];
    float4 v = ld4(&x[(size_t)i << 2]);
    float r0 = fmaxf((v.x - m) * rs * sw + sb, 0.f);
    float r1 = fmaxf((v.y - m) * rs * sw + sb, 0.f);
    float r2 = fmaxf((v.z - m) * rs * sw + sb, 0.f);
    float r3 = fmaxf((v.w - m) * rs * sw + sb, 0.f);
    o[(size_t)(px0 + 0) * 256 + c] = f2bf(r0);
    o[(size_t)(px0 + 1) * 256 + c] = f2bf(r1);
    o[(size_t)(px0 + 2) * 256 + c] = f2bf(r2);
    o[(size_t)(px0 + 3) * 256 + c] = f2bf(r3);
}

// ---------------- groupnorm apply + relu -> f32 NCHW ----------------
__global__ void gnapply_f_k(const float* __restrict__ x, const float* __restrict__ st,
                            const float* __restrict__ w, const float* __restrict__ b,
                            float* __restrict__ o)
{
    int i = blockIdx.x * blockDim.x + threadIdx.x;
    if (i >= 262144) return;
    int c = i >> 10;
    int g = c >> 3;
    float m = st[g * 2], rs = st[g * 2 + 1];
    float sw = w[c], sb = b[c];
    float4 v = ld4(&x[(size_t)i << 2]);
    float4 r;
    r.x = fmaxf((v.x - m) * rs * sw + sb, 0.f);
    r.y = fmaxf((v.y - m) * rs * sw + sb, 0.f);
    r.z = fmaxf((v.z - m) * rs * sw + sb, 0.f);
    r.w = fmaxf((v.w - m) * rs * sw + sb, 0.f);
    *(float4*)&o[(size_t)i << 2] = r;
}

// ---------------- host launcher ----------------
extern "C" void kernel_launch(void* const* d_in, const int* in_sizes, int n_in,
                              void* d_out, int out_size, void* d_ws, size_t ws_size,
                              hipStream_t stream)
{
    (void)in_sizes; (void)n_in; (void)out_size; (void)ws_size;
    const float* feat0 = (const float*)d_in[0];
    const float* feat1 = (const float*)d_in[1];
    const float* feat2 = (const float*)d_in[2];
    const float* in0_w = (const float*)d_in[3];
    const float* in0_b = (const float*)d_in[4];
    const float* in1_w = (const float*)d_in[5];
    const float* in1_b = (const float*)d_in[6];
    const float* in2_w = (const float*)d_in[7];
    const float* in2_b = (const float*)d_in[8];
    const float* off_w = (const float*)d_in[9];
    const float* off_b = (const float*)d_in[10];
    const float* aw_w  = (const float*)d_in[11];
    const float* aw_b  = (const float*)d_in[12];
    const float* vp_w  = (const float*)d_in[13];
    const float* vp_b  = (const float*)d_in[14];
    const float* op_w  = (const float*)d_in[15];
    const float* op_b  = (const float*)d_in[16];
    const float* n1_w  = (const float*)d_in[17];
    const float* n1_b  = (const float*)d_in[18];
    const float* ff1_w = (const float*)d_in[19];
    const float* ff1_b = (const float*)d_in[20];
    const float* ff2_w = (const float*)d_in[21];
    const float* ff2_b = (const float*)d_in[22];
    const float* n2_w  = (const float*)d_in[23];
    const float* n2_b  = (const float*)d_in[24];
    const float* fn_w  = (const float*)d_in[25];
    const float* fn_b  = (const float*)d_in[26];
    const float* lat_w = (const float*)d_in[27];
    const float* lat_b = (const float*)d_in[28];
    const float* out_w = (const float*)d_in[29];
    const float* gnw   = (const float*)d_in[30];
    const float* gnb   = (const float*)d_in[31];
    float* out = (float*)d_out;

    // ---- workspace (~59 MB; 69.6 MB proven safe, 73.5 MB proven unsafe) ----
    float* ws     = (float*)d_ws;
    float* src    = ws;                 // 1376256
    float* pos    = src  + 1376256;     // 1376256 (pong alias after encoder)
    float* tmp    = pos  + 1376256;     // 1376256
    float* valbuf = tmp  + 1376256;     // 1376256 (valb bf16 | latb bf16)
    float* oab    = valbuf + 1376256;   // 1548288 (raw off|aw scores per token)
    float* stats  = oab  + 1548288;     // 64
    float* boa    = stats + 64;         // 1728
    float* pong   = pos;                // alias

    unsigned short* valb = (unsigned short*)valbuf;
    unsigned short* latb = (unsigned short*)(valbuf + 688128);

    unsigned short* ub = (unsigned short*)(boa + 1728);
    unsigned short* srcb  = ub; ub += 1376256;
    unsigned short* qbb   = ub; ub += 1376256;  // pingb alias after encoder
    unsigned short* msdb  = ub; ub += 1376256;
    unsigned short* ffhb  = ub; ub += 5505024;  // hosts fT0/1/2 during setup
    unsigned short* w_oa  = ub; ub += 442368;
    unsigned short* w_vp  = ub; ub += 393216;   // contiguous run for cvtall:
    unsigned short* w_op  = ub; ub += 393216;   //   vp|op|ff1|ff2|in0|in1|in2|lat
    unsigned short* w_ff1 = ub; ub += 1572864;
    unsigned short* w_ff2 = ub; ub += 1572864;
    unsigned short* w_in0 = ub; ub += 65536;
    unsigned short* w_in1 = ub; ub += 131072;
    unsigned short* w_in2 = ub; ub += 262144;
    unsigned short* w_lat = ub; ub += 65536;
    unsigned short* wcb   = ub; ub += 1769472;

    unsigned short* fT0 = ffhb;
    unsigned short* fT1 = ffhb + 1048576;
    unsigned short* fT2 = ffhb + 1572864;
    unsigned short* pingb = qbb;

    // ---- setup ----
    pack_oa_k<<<1728, 256, 0, stream>>>(off_w, off_b, aw_w, aw_b, w_oa, boa);
    wconv_k<<<6912, 256, 0, stream>>>(out_w, wcb);
    cvtall_k<<<4352, 256, 0, stream>>>(vp_w, op_w, ff1_w, ff2_w, in0_w, in1_w, in2_w, lat_w, w_vp);
    cvtT_k<<<dim3(128, 8), dim3(32, 8), 0, stream>>>(feat0, fT0, 256, 4096);
    cvtT_k<<<dim3(32, 16), dim3(32, 8), 0, stream>>>(feat1, fT1, 512, 1024);
    cvtT_k<<<dim3(8, 32),  dim3(32, 8), 0, stream>>>(feat2, fT2, 1024, 256);
    posenc_k<<<2688, 256, 0, stream>>>(pos);

    // ---- input projections ----
    bgemm_k<2,false><<<dim3(4,64), 256, 0, stream>>>(fT0, w_in0, in0_b, src,            srcb,            4096, 256, 256);
    bgemm_k<2,false><<<dim3(4,16), 256, 0, stream>>>(fT1, w_in1, in1_b, src + 4096*256, srcb + 4096*256, 1024, 256, 512);
    bgemm_k<2,false><<<dim3(4,4),  256, 0, stream>>>(fT2, w_in2, in2_b, src + 5120*256, srcb + 5120*256, 256,  256, 1024);
    addb_k<<<1344, 256, 0, stream>>>(src, pos, qbb, 344064);

    // ---- encoder layers ----
    for (int i = 0; i < 6; i++) {
        bgemm_k<0,false><<<dim3(5,84), 256, 0, stream>>>(qbb,  w_oa + i*73728, boa + i*288, oab, nullptr, 5376, 288, 256);
        bgemm_k<1,false><<<dim3(4,84), 256, 0, stream>>>(srcb, w_vp + i*65536, vp_b + i*256, nullptr, valb, 5376, 256, 256);
        msdef_k<<<672, 256, 0, stream>>>(valb, oab, msdb);
        bgemm_k<0,false><<<dim3(4,84), 256, 0, stream>>>(msdb, w_op + i*65536, op_b + i*256, tmp, nullptr, 5376, 256, 256);
        ln_k<true,false><<<1344, 256, 0, stream>>>(src, tmp, n1_w + i*256, n1_b + i*256, srcb, nullptr, nullptr);
        bgemm_k<1,true ><<<dim3(16,84),256, 0, stream>>>(srcb, w_ff1 + i*262144, ff1_b + i*1024, nullptr, ffhb, 5376, 1024, 256);
        bgemm_k<0,false><<<dim3(4,84), 256, 0, stream>>>(ffhb, w_ff2 + i*262144, ff2_b + i*256, tmp, nullptr, 5376, 256, 1024);
        if (i < 5)
            ln_k<true,true><<<1344, 256, 0, stream>>>(src, tmp, n2_w + i*256, n2_b + i*256, srcb, pos, qbb);
        else
            ln_k<true,false><<<1344, 256, 0, stream>>>(src, tmp, n2_w + i*256, n2_b + i*256, srcb, nullptr, nullptr);
    }
    ln_k<false,false><<<1344, 256, 0, stream>>>(src, nullptr, fn_w, fn_b, srcb, nullptr, nullptr);

    // ---- mems -> d_out (NCHW) ----
    tr_k<<<dim3(128,8), dim3(32,8), 0, stream>>>(src,           out + 1048576, 4096);
    tr_k<<<dim3(32,8),  dim3(32,8), 0, stream>>>(src + 1048576, out + 2097152, 1024);
    tr_k<<<dim3(8,8),   dim3(32,8), 0, stream>>>(src + 1310720, out + 2359296, 256);

    // ---- lateral 1x1 -> bf16 NHWC ----
    bgemm_k<1,false><<<dim3(4,64), 256, 0, stream>>>(srcb, w_lat, lat_b, nullptr, latb, 4096, 256, 256);

    // ---- 3x (conv3x3 MFMA -> groupnorm -> relu) ----
    conv3b_k<<<dim3(64,4), 256, 0, stream>>>(latb, wcb, pong);
    gnstats_k<<<32, 256, 0, stream>>>(pong, stats);
    gnapply_b_k<<<1024, 256, 0, stream>>>(pong, stats, gnw, gnb, pingb);

    conv3b_k<<<dim3(64,4), 256, 0, stream>>>(pingb, wcb + 589824, pong);
    gnstats_k<<<32, 256, 0, stream>>>(pong, stats);
    gnapply_b_k<<<1024, 256, 0, stream>>>(pong, stats, gnw + 256, gnb + 256, pingb);

    conv3b_k<<<dim3(64,4), 256, 0, stream>>>(pingb, wcb + 1179648, pong);
    gnstats_k<<<32, 256, 0, stream>>>(pong, stats);
    gnapply_f_k<<<1024, 256, 0, stream>>>(pong, stats, gnw + 512, gnb + 512, out);
}

// Round 6
// 642.347 us; speedup vs baseline: 3.8880x; 1.0261x over previous
//
#include <hip/hip_runtime.h>
#include <math.h>

#define LTOT 5376

typedef __attribute__((ext_vector_type(8))) __bf16 bf16x8;
typedef __attribute__((ext_vector_type(4))) float f32x4;
typedef __attribute__((ext_vector_type(8))) unsigned short us8;
typedef __attribute__((ext_vector_type(4))) unsigned short us4;

static __device__ __forceinline__ float4 ld4(const float* p) { return *(const float4*)p; }

static __device__ __forceinline__ unsigned short f2bf(float f) {
    unsigned int u = __float_as_uint(f);
    return (unsigned short)((u + 0x7fffu + ((u >> 16) & 1u)) >> 16);
}
static __device__ __forceinline__ float bf2f(unsigned short s) {
    return __uint_as_float(((unsigned int)s) << 16);
}

// async global->LDS, 16B per lane; lds base wave-uniform (HW adds lane*16)
static __device__ __forceinline__ void gl16(const unsigned short* g, unsigned short* l) {
    __builtin_amdgcn_global_load_lds(
        (const __attribute__((address_space(1))) unsigned int*)g,
        (__attribute__((address_space(3))) unsigned int*)l, 16, 0, 0);
}

// ================= bf16 MFMA GEMM core, 3-buffer counted-vmcnt pipeline =================
// C(M,N) = A(.,K) @ B(N,K)^T + bias(N). 64x64 tile, BK=64.
// 256 thr = 4 waves (2x2), wave 32x32. LDS row=64sh(128B)=8 chunks; chunk c at slot c^(r&7).
// Pipeline: 2 stages in flight; raw s_barrier + counted vmcnt (4 gl16 per stage per thread).
// omode: 0 = f32 C1, 1 = bf16 C2, 2 = both, 3 = both + qb = f2bf(v + pos)
__device__ __forceinline__ void gemm_core(
    const unsigned short* __restrict__ A,
    const unsigned short* __restrict__ B,
    const float* __restrict__ bias,
    float* __restrict__ C1, unsigned short* __restrict__ C2,
    const float* __restrict__ posf, unsigned short* __restrict__ qb,
    unsigned short* As, unsigned short* Bs,     // each 3*4096 shorts
    int m0, int mo0, int n0, int N, int K, int omode, int relu)
{
    const int tid  = threadIdx.x;
    const int wave = tid >> 6;
    const int lane = tid & 63;
    const int wm   = (wave >> 1) * 32;
    const int wn   = (wave & 1) * 32;
    const int fr   = lane & 15;
    const int ko   = lane >> 4;

    const int q0 = tid, q1 = tid + 256;
    const int r0 = q0 >> 3, c0v = (q0 & 7) ^ (r0 & 7);
    const int r1 = q1 >> 3, c1v = (q1 & 7) ^ (r1 & 7);
    const unsigned short* a0 = A + (size_t)(m0 + r0) * K + (c0v << 3);
    const unsigned short* a1 = A + (size_t)(m0 + r1) * K + (c1v << 3);
    int bn0 = n0 + r0; if (bn0 > N - 1) bn0 = N - 1;
    int bn1 = n0 + r1; if (bn1 > N - 1) bn1 = N - 1;
    const unsigned short* b0 = B + (size_t)bn0 * K + (c0v << 3);
    const unsigned short* b1 = B + (size_t)bn1 * K + (c1v << 3);
    const int wb = wave << 9;

    f32x4 acc[2][2] = {};
    const int nt = K >> 6;   // >= 4 for all call sites

    auto stage = [&](int buf, int t) {
        const int kof = t << 6;
        gl16(a0 + kof, As + buf * 4096 + wb);
        gl16(a1 + kof, As + buf * 4096 + 2048 + wb);
        gl16(b0 + kof, Bs + buf * 4096 + wb);
        gl16(b1 + kof, Bs + buf * 4096 + 2048 + wb);
    };

    stage(0, 0);
    stage(1, 1);
    asm volatile("s_waitcnt vmcnt(4)" ::: "memory");   // tile 0 resident
    __builtin_amdgcn_s_barrier();
    __builtin_amdgcn_sched_barrier(0);

    for (int t = 0; t < nt; t++) {
        if (t + 2 < nt) stage((t + 2) % 3, t + 2);     // overwrites buf used by tile t-1 (drained at last barrier)
        const unsigned short* Ab = As + (t % 3) * 4096;
        const unsigned short* Bb = Bs + (t % 3) * 4096;
        #pragma unroll
        for (int sub = 0; sub < 2; sub++) {
            bf16x8 af[2], bfr[2];
            const int kk = (sub << 2) + ko;
            #pragma unroll
            for (int i = 0; i < 2; i++) {
                int r = wm + i * 16 + fr;
                af[i] = *(const bf16x8*)&Ab[(r << 6) + ((kk ^ (r & 7)) << 3)];
                int c = wn + i * 16 + fr;
                bfr[i] = *(const bf16x8*)&Bb[(c << 6) + ((kk ^ (c & 7)) << 3)];
            }
            #pragma unroll
            for (int i = 0; i < 2; i++)
                #pragma unroll
                for (int j = 0; j < 2; j++)
                    acc[i][j] = __builtin_amdgcn_mfma_f32_16x16x32_bf16(af[i], bfr[j], acc[i][j], 0, 0, 0);
        }
        if (t + 1 < nt) {
            // drain own ds_reads (readers-before-writers), then wait tile t+1 loads
            if (t + 2 < nt) asm volatile("s_waitcnt vmcnt(4) lgkmcnt(0)" ::: "memory");
            else            asm volatile("s_waitcnt vmcnt(0) lgkmcnt(0)" ::: "memory");
            __builtin_amdgcn_s_barrier();
            __builtin_amdgcn_sched_barrier(0);
        }
    }

    #pragma unroll
    for (int j = 0; j < 2; j++) {
        int col = n0 + wn + j * 16 + fr;
        if (col >= N) continue;
        float cb = bias[col];
        #pragma unroll
        for (int i = 0; i < 2; i++) {
            #pragma unroll
            for (int r = 0; r < 4; r++) {
                int row = mo0 + wm + i * 16 + ko * 4 + r;
                float v = acc[i][j][r] + cb;
                if (relu) v = fmaxf(v, 0.f);
                size_t off = (size_t)row * N + col;
                if (omode == 0)      C1[off] = v;
                else if (omode == 1) C2[off] = f2bf(v);
                else if (omode == 2) { C1[off] = v; C2[off] = f2bf(v); }
                else { C1[off] = v; C2[off] = f2bf(v); qb[off] = f2bf(v + posf[off]); }
            }
        }
    }
}

// generic wrapper
__global__ __launch_bounds__(256) void bgemm_k(
    const unsigned short* __restrict__ A, const unsigned short* __restrict__ B,
    const float* __restrict__ bias, float* __restrict__ C1, unsigned short* __restrict__ C2,
    int N, int K, int omode, int relu)
{
    __shared__ unsigned short As[3 * 4096], Bs[3 * 4096];
    int m = blockIdx.y * 64;
    gemm_core(A, B, bias, C1, C2, nullptr, nullptr, As, Bs, m, m, blockIdx.x * 64, N, K, omode, relu);
}

// fused per-layer head: oa-gemm (qbb -> oab, N=288) + vp-gemm (srcb -> valb, N=256)
__global__ __launch_bounds__(256) void oavp_k(
    const unsigned short* __restrict__ qbb, const unsigned short* __restrict__ woa,
    const float* __restrict__ boa, float* __restrict__ oab,
    const unsigned short* __restrict__ srcb, const unsigned short* __restrict__ wvp,
    const float* __restrict__ bvp, unsigned short* __restrict__ valb)
{
    __shared__ unsigned short As[3 * 4096], Bs[3 * 4096];
    const int bx = blockIdx.x;
    const int m = blockIdx.y * 64;
    if (bx < 5)
        gemm_core(qbb,  woa, boa, oab, nullptr, nullptr, nullptr, As, Bs, m, m, bx * 64, 288, 256, 0, 0);
    else
        gemm_core(srcb, wvp, bvp, nullptr, valb, nullptr, nullptr, As, Bs, m, m, (bx - 5) * 64, 256, 256, 1, 0);
}

// fused input projections (3 levels, different K) + qbb = src + pos epilogue
__global__ __launch_bounds__(256) void inproj_k(
    const unsigned short* __restrict__ fT0, const unsigned short* __restrict__ w0, const float* __restrict__ b0,
    const unsigned short* __restrict__ fT1, const unsigned short* __restrict__ w1, const float* __restrict__ b1,
    const unsigned short* __restrict__ fT2, const unsigned short* __restrict__ w2, const float* __restrict__ b2,
    float* __restrict__ src, unsigned short* __restrict__ srcb,
    const float* __restrict__ posf, unsigned short* __restrict__ qbb)
{
    __shared__ unsigned short As[3 * 4096], Bs[3 * 4096];
    const int by = blockIdx.y;
    const int n0 = blockIdx.x * 64;
    if (by < 64)
        gemm_core(fT0, w0, b0, src, srcb, posf, qbb, As, Bs, by * 64, by * 64, n0, 256, 256, 3, 0);
    else if (by < 80)
        gemm_core(fT1, w1, b1, src, srcb, posf, qbb, As, Bs, (by - 64) * 64, 4096 + (by - 64) * 64, n0, 256, 512, 3, 0);
    else
        gemm_core(fT2, w2, b2, src, srcb, posf, qbb, As, Bs, (by - 80) * 64, 5120 + (by - 80) * 64, n0, 256, 1024, 3, 0);
}

// ---------------- fused fp32 -> bf16 convert for all plain weights ----------------
__global__ void cvtall_k(const float* __restrict__ s0, const float* __restrict__ s1,
                         const float* __restrict__ s2, const float* __restrict__ s3,
                         const float* __restrict__ s4, const float* __restrict__ s5,
                         const float* __restrict__ s6, const float* __restrict__ s7,
                         unsigned short* __restrict__ d)
{
    int i = blockIdx.x * blockDim.x + threadIdx.x;
    if (i >= 1114112) return;
    const float* s; int off;
    if      (i <   98304) { s = s0; off = 0; }
    else if (i <  196608) { s = s1; off = 98304; }
    else if (i <  589824) { s = s2; off = 196608; }
    else if (i <  983040) { s = s3; off = 589824; }
    else if (i <  999424) { s = s4; off = 983040; }
    else if (i < 1032192) { s = s5; off = 999424; }
    else if (i < 1097728) { s = s6; off = 1032192; }
    else                  { s = s7; off = 1097728; }
    float4 v = ld4(&s[(size_t)(i - off) << 2]);
    us4 r = { f2bf(v.x), f2bf(v.y), f2bf(v.z), f2bf(v.w) };
    *(us4*)&d[(size_t)i << 2] = r;
}

// ---------------- (Ci,P) fp32 -> (P,Ci) bf16 transpose ----------------
__global__ void cvtT_k(const float* __restrict__ src, unsigned short* __restrict__ dst, int Ci, int P)
{
    __shared__ float t[32][33];
    int c0 = blockIdx.y * 32, p0 = blockIdx.x * 32;
    int x = threadIdx.x, y = threadIdx.y;
    for (int i = y; i < 32; i += 8)
        t[i][x] = src[(size_t)(c0 + i) * P + p0 + x];
    __syncthreads();
    for (int i = y; i < 32; i += 8)
        dst[(size_t)(p0 + i) * Ci + c0 + x] = f2bf(t[x][i]);
}

// ---------------- pack off|aw weights+bias per layer ----------------
__global__ void pack_oa_k(const float* __restrict__ off_w, const float* __restrict__ off_b,
                          const float* __restrict__ aw_w,  const float* __restrict__ aw_b,
                          unsigned short* __restrict__ w_oa, float* __restrict__ b_oa)
{
    int idx = blockIdx.x * blockDim.x + threadIdx.x;
    if (idx >= 6 * 288 * 256) return;
    int i = idx / 73728;
    int r = idx - i * 73728;
    int n = r >> 8;
    int k = r & 255;
    float v = (n < 192) ? off_w[((size_t)i * 192 + n) * 256 + k]
                        : aw_w[((size_t)i * 96 + (n - 192)) * 256 + k];
    w_oa[idx] = f2bf(v);
    if (k == 0)
        b_oa[i * 288 + n] = (n < 192) ? off_b[i * 192 + n] : aw_b[i * 96 + (n - 192)];
}

// ---------------- conv weight repack ----------------
__global__ void wconv_k(const float* __restrict__ out_w, unsigned short* __restrict__ wcb)
{
    int idx = blockIdx.x * blockDim.x + threadIdx.x;
    if (idx >= 3 * 589824) return;
    int c   = idx / 589824;
    int r   = idx - c * 589824;
    int icc = r / 73728;
    int r2  = r - icc * 73728;
    int oc  = r2 / 288;
    int r3  = r2 - oc * 288;
    int tap = r3 >> 5;
    int sl  = r3 & 31;
    int ic  = icc * 32 + (((sl >> 3) ^ ((oc >> 1) & 3)) << 3) + (sl & 7);
    wcb[idx] = f2bf(out_w[(((size_t)(c * 256 + oc)) * 256 + ic) * 9 + tap]);
}

// ---------------- sine positional encoding ----------------
__global__ void posenc_k(float* __restrict__ pos)
{
    int idx = blockIdx.x * blockDim.x + threadIdx.x;
    if (idx >= LTOT * 128) return;
    int l = idx >> 7;
    int pr = idx & 127;
    int half = pr >> 6;
    int j = pr & 63;
    int HW, sh, p;
    if (l < 4096)      { HW = 64; sh = 6; p = l; }
    else if (l < 5120) { HW = 32; sh = 5; p = l - 4096; }
    else               { HW = 16; sh = 4; p = l - 5120; }
    int y = p >> sh;
    int x = p & (HW - 1);
    float T = powf(10000.f, (float)j * (1.f / 64.f));
    float coord = (half == 0) ? (float)(y + 1) : (float)(x + 1);
    float v = coord / ((float)HW + 1e-6f) * 6.283185307179586f;
    float arg = v / T;
    size_t base = (size_t)l * 256 + half * 128 + (j << 1);
    pos[base]     = sinf(arg);
    pos[base + 1] = cosf(arg);
}

// ---------------- multi-scale deformable sampling, softmax fused ----------------
__global__ __launch_bounds__(256) void msdef_k(
    const unsigned short* __restrict__ valb, const float* __restrict__ oab,
    unsigned short* __restrict__ out)
{
    __shared__ float sw[8 * 288];
    const int tid = threadIdx.x;
    const int bl = blockIdx.x;
    #pragma unroll
    for (int id = tid; id < 576; id += 256)
        ((float4*)sw)[id] = ((const float4*)(oab + (size_t)bl * 2304))[id];
    __syncthreads();

    const int p = tid >> 5;
    const int t = tid & 31;
    const int l = bl * 8 + p;
    const int h = t >> 2;
    const int co = (t & 3) << 3;
    const float* mo = sw + p * 288;

    float aw_r[12];
    {
        const float* sc = mo + 192 + h * 12;
        float mx = -1e30f;
        #pragma unroll
        for (int j = 0; j < 12; j++) { aw_r[j] = sc[j]; mx = fmaxf(mx, aw_r[j]); }
        float su = 0.f;
        #pragma unroll
        for (int j = 0; j < 12; j++) { aw_r[j] = expf(aw_r[j] - mx); su += aw_r[j]; }
        float inv = 1.f / su;
        #pragma unroll
        for (int j = 0; j < 12; j++) aw_r[j] *= inv;
    }

    float rx, ry;
    {
        int HW, sh, q;
        if (l < 4096)      { HW = 64; sh = 6; q = l; }
        else if (l < 5120) { HW = 32; sh = 5; q = l - 4096; }
        else               { HW = 16; sh = 4; q = l - 5120; }
        int y = q >> sh;
        int x = q & (HW - 1);
        rx = (x + 0.5f) / (float)HW;
        ry = (y + 0.5f) / (float)HW;
    }

    const int starts[3] = {0, 4096, 5120};
    const int dims[3]   = {64, 32, 16};
    float acc[8] = {};
    #pragma unroll
    for (int s = 0; s < 3; s++) {
        const int D = dims[s];
        const int st = starts[s];
        #pragma unroll
        for (int pt = 0; pt < 4; pt++) {
            float a  = aw_r[(s << 2) + pt];
            float px = rx * D + mo[h * 24 + (s << 3) + (pt << 1)]     - 0.5f;
            float py = ry * D + mo[h * 24 + (s << 3) + (pt << 1) + 1] - 0.5f;
            float x0f = floorf(px), y0f = floorf(py);
            float lx = px - x0f, ly = py - y0f;
            int x0 = (int)x0f, y0 = (int)y0f;
            float w00 = a * (1.f - lx) * (1.f - ly);
            float w10 = a * lx * (1.f - ly);
            float w01 = a * (1.f - lx) * ly;
            float w11 = a * lx * ly;
            #pragma unroll
            for (int cy = 0; cy < 2; cy++) {
                int yi = y0 + cy;
                if (yi < 0 || yi >= D) continue;
                #pragma unroll
                for (int cx = 0; cx < 2; cx++) {
                    int xi = x0 + cx;
                    if (xi < 0 || xi >= D) continue;
                    float w = cy ? (cx ? w11 : w01) : (cx ? w10 : w00);
                    us8 v = *(const us8*)&valb[((size_t)(st + yi * D + xi) << 8) + (h << 5) + co];
                    #pragma unroll
                    for (int e = 0; e < 8; e++)
                        acc[e] = fmaf(w, bf2f(v[e]), acc[e]);
                }
            }
        }
    }
    us8 r;
    #pragma unroll
    for (int e = 0; e < 8; e++) r[e] = f2bf(acc[e]);
    *(us8*)&out[((size_t)l << 8) + (h << 5) + co] = r;
}

// ---------------- layernorm (+residual), in-place fp32 + bf16 copy (+ q=out+pos) ----------------
template<bool HAS_ADD, bool HAS_POS>
__global__ __launch_bounds__(256) void ln_k(float* __restrict__ src, const float* __restrict__ add,
                                            const float* __restrict__ w, const float* __restrict__ b,
                                            unsigned short* __restrict__ outb,
                                            const float* __restrict__ posf,
                                            unsigned short* __restrict__ qbout)
{
    int row = blockIdx.x * 4 + (threadIdx.x >> 6);
    int lane = threadIdx.x & 63;
    size_t base = (size_t)row * 256 + (lane << 2);
    float4 x = ld4(&src[base]);
    if (HAS_ADD) {
        float4 a = ld4(&add[base]);
        x.x += a.x; x.y += a.y; x.z += a.z; x.w += a.w;
    }
    float s = x.x + x.y + x.z + x.w;
    #pragma unroll
    for (int o = 32; o > 0; o >>= 1) s += __shfl_xor(s, o, 64);
    float m = s * (1.f / 256.f);
    float d0 = x.x - m, d1 = x.y - m, d2 = x.z - m, d3 = x.w - m;
    float v = d0 * d0 + d1 * d1 + d2 * d2 + d3 * d3;
    #pragma unroll
    for (int o = 32; o > 0; o >>= 1) v += __shfl_xor(v, o, 64);
    float rs = rsqrtf(v * (1.f / 256.f) + 1e-5f);
    float4 wv = ld4(&w[lane << 2]);
    float4 bv = ld4(&b[lane << 2]);
    float4 o4;
    o4.x = d0 * rs * wv.x + bv.x;
    o4.y = d1 * rs * wv.y + bv.y;
    o4.z = d2 * rs * wv.z + bv.z;
    o4.w = d3 * rs * wv.w + bv.w;
    *(float4*)&src[base] = o4;
    us4 r = { f2bf(o4.x), f2bf(o4.y), f2bf(o4.z), f2bf(o4.w) };
    *(us4*)&outb[base] = r;
    if (HAS_POS) {
        float4 p4 = ld4(&posf[base]);
        us4 q = { f2bf(o4.x + p4.x), f2bf(o4.y + p4.y), f2bf(o4.z + p4.z), f2bf(o4.w + p4.w) };
        *(us4*)&qbout[base] = q;
    }
}

// ---------------- (HW,256) -> (256,HW) transpose (fp32) ----------------
__global__ void tr_k(const float* __restrict__ src, float* __restrict__ dst, int HW)
{
    __shared__ float t[32][33];
    int p0 = blockIdx.x * 32, c0 = blockIdx.y * 32;
    int x = threadIdx.x, y = threadIdx.y;
    for (int i = y; i < 32; i += 8)
        t[i][x] = src[(size_t)(p0 + i) * 256 + c0 + x];
    __syncthreads();
    for (int i = y; i < 32; i += 8)
        dst[(size_t)(c0 + i) * HW + p0 + x] = t[x][i];
}

// ---------------- 3x3 conv via bf16 MFMA implicit GEMM ----------------
__global__ __launch_bounds__(256) void conv3b_k(const unsigned short* __restrict__ inb,
                                                const unsigned short* __restrict__ wcb,
                                                float* __restrict__ out)
{
    __shared__ __align__(16) unsigned char smem[43776];
    unsigned short* sIn = (unsigned short*)smem;
    unsigned short* sW  = (unsigned short*)(smem + 6912);
    float* sO = (float*)smem;

    const int tid = threadIdx.x;
    const int mb = blockIdx.x;
    const int y0 = (mb >> 2) << 2;
    const int x0 = (mb & 3) << 4;
    const int oc0 = blockIdx.y << 6;
    const int wave = tid >> 6, lane = tid & 63;
    const int wm = (wave >> 1) * 32, wn = (wave & 1) * 32;
    const int fr = lane & 15, ko = lane >> 4;

    f32x4 acc[2][2] = {};

    for (int icc = 0; icc < 8; icc++) {
        __syncthreads();
        #pragma unroll
        for (int id = tid; id < 432; id += 256) {
            int pxi = id >> 2, ch = id & 3;
            int r = pxi / 18, s = pxi - r * 18;
            int gy = y0 - 1 + r, gx = x0 - 1 + s;
            us8 v = {};
            if (gy >= 0 && gy < 64 && gx >= 0 && gx < 64)
                v = *(const us8*)&inb[((size_t)(gy * 64 + gx) << 8) + (icc << 5) + (ch << 3)];
            *(us8*)&sIn[(pxi << 5) + ((ch ^ ((s >> 1) & 3)) << 3)] = v;
        }
        const unsigned short* wsrc = wcb + (((size_t)icc * 256 + oc0) * 9 << 5);
        #pragma unroll
        for (int id = tid; id < 2304; id += 256)
            *(us8*)&sW[id << 3] = *(const us8*)&wsrc[id << 3];
        __syncthreads();

        #pragma unroll
        for (int tap = 0; tap < 9; tap++) {
            const int ky = tap / 3, kx = tap - ky * 3;
            bf16x8 a[2], b[2];
            #pragma unroll
            for (int i = 0; i < 2; i++) {
                int px = wm + i * 16 + fr;
                int r = (px >> 4) + ky;
                int s = (px & 15) + kx;
                a[i] = *(const bf16x8*)&sIn[(((r * 18 + s)) << 5) + ((ko ^ ((s >> 1) & 3)) << 3)];
            }
            #pragma unroll
            for (int j = 0; j < 2; j++) {
                int oc = wn + j * 16 + fr;
                b[j] = *(const bf16x8*)&sW[(((oc * 9) + tap) << 5) + ((ko ^ ((oc >> 1) & 3)) << 3)];
            }
            #pragma unroll
            for (int i = 0; i < 2; i++)
                #pragma unroll
                for (int j = 0; j < 2; j++)
                    acc[i][j] = __builtin_amdgcn_mfma_f32_16x16x32_bf16(a[i], b[j], acc[i][j], 0, 0, 0);
        }
    }

    __syncthreads();
    #pragma unroll
    for (int i = 0; i < 2; i++)
        #pragma unroll
        for (int j = 0; j < 2; j++) {
            int oc = wn + j * 16 + fr;
            int pxb = wm + i * 16 + ko * 4;
            *(f32x4*)&sO[oc * 68 + pxb] = acc[i][j];
        }
    __syncthreads();
    {
        int oc_r = tid >> 2, yy = tid & 3;
        float* dst = &out[(size_t)(oc0 + oc_r) * 4096 + (y0 + yy) * 64 + x0];
        const float* srcl = &sO[oc_r * 68 + yy * 16];
        #pragma unroll
        for (int q = 0; q < 4; q++)
            *(float4*)&dst[q * 4] = *(const float4*)&srcl[q * 4];
    }
}

// ---------------- groupnorm stats ----------------
__global__ __launch_bounds__(256) void gnstats_k(const float* __restrict__ x, float* __restrict__ st)
{
    int g = blockIdx.x;
    const float* p = x + (size_t)g * 8 * 4096;
    float s = 0.f, ss = 0.f;
    for (int i = threadIdx.x * 4; i < 32768; i += 1024) {
        float4 v = ld4(&p[i]);
        s  += v.x + v.y + v.z + v.w;
        ss += v.x * v.x + v.y * v.y + v.z * v.z + v.w * v.w;
    }
    #pragma unroll
    for (int o = 32; o > 0; o >>= 1) {
        s  += __shfl_xor(s, o, 64);
        ss += __shfl_xor(ss, o, 64);
    }
    __shared__ float rs[4], rss[4];
    int wid = threadIdx.x >> 6;
    if ((threadIdx.x & 63) == 0) { rs[wid] = s; rss[wid] = ss; }
    __syncthreads();
    if (threadIdx.x == 0) {
        float S = rs[0] + rs[1] + rs[2] + rs[3];
        float SS = rss[0] + rss[1] + rss[2] + rss[3];
        float m = S * (1.f / 32768.f);
        float var = SS * (1.f / 32768.f) - m * m;
        st[g * 2] = m;
        st[g * 2 + 1] = rsqrtf(var + 1e-5f);
    }
}

// ---------------- groupnorm apply + relu -> bf16 NHWC ----------------
__global__ void gnapply_b_k(const float* __restrict__ x, const float* __restrict__ st,
                            const float* __restrict__ w, const float* __restrict__ b,
                            unsigned short* __restrict__ o)
{
    int i = blockIdx.x * blockDim.x + threadIdx.x;
    if (i >= 262144) return;
    int c = i >> 10;
    int g = c >> 3;
    int px0 = (i & 1023) << 2;
    float m = st[g * 2], rs = st[g * 2 + 1];
    float sw = w[c], sb = b[c];
    float4 v = ld4(&x[(size_t)i << 2]);
    float r0 = fmaxf((v.x - m) * rs * sw + sb, 0.f);
    float r1 = fmaxf((v.y - m) * rs * sw + sb, 0.f);
    float r2 = fmaxf((v.z - m) * rs * sw + sb, 0.f);
    float r3 = fmaxf((v.w - m) * rs * sw + sb, 0.f);
    o[(size_t)(px0 + 0) * 256 + c] = f2bf(r0);
    o[(size_t)(px0 + 1) * 256 + c] = f2bf(r1);
    o[(size_t)(px0 + 2) * 256 + c] = f2bf(r2);
    o[(size_t)(px0 + 3) * 256 + c] = f2bf(r3);
}

// ---------------- groupnorm apply + relu -> f32 NCHW ----------------
__global__ void gnapply_f_k(const float* __restrict__ x, const float* __restrict__ st,
                            const float* __restrict__ w, const float* __restrict__ b,
                            float* __restrict__ o)
{
    int i = blockIdx.x * blockDim.x + threadIdx.x;
    if (i >= 262144) return;
    int c = i >> 10;
    int g = c >> 3;
    float m = st[g * 2], rs = st[g * 2 + 1];
    float sw = w[c], sb = b[c];
    float4 v = ld4(&x[(size_t)i << 2]);
    float4 r;
    r.x = fmaxf((v.x - m) * rs * sw + sb, 0.f);
    r.y = fmaxf((v.y - m) * rs * sw + sb, 0.f);
    r.z = fmaxf((v.z - m) * rs * sw + sb, 0.f);
    r.w = fmaxf((v.w - m) * rs * sw + sb, 0.f);
    *(float4*)&o[(size_t)i << 2] = r;
}

// ---------------- host launcher ----------------
extern "C" void kernel_launch(void* const* d_in, const int* in_sizes, int n_in,
                              void* d_out, int out_size, void* d_ws, size_t ws_size,
                              hipStream_t stream)
{
    (void)in_sizes; (void)n_in; (void)out_size; (void)ws_size;
    const float* feat0 = (const float*)d_in[0];
    const float* feat1 = (const float*)d_in[1];
    const float* feat2 = (const float*)d_in[2];
    const float* in0_w = (const float*)d_in[3];
    const float* in0_b = (const float*)d_in[4];
    const float* in1_w = (const float*)d_in[5];
    const float* in1_b = (const float*)d_in[6];
    const float* in2_w = (const float*)d_in[7];
    const float* in2_b = (const float*)d_in[8];
    const float* off_w = (const float*)d_in[9];
    const float* off_b = (const float*)d_in[10];
    const float* aw_w  = (const float*)d_in[11];
    const float* aw_b  = (const float*)d_in[12];
    const float* vp_w  = (const float*)d_in[13];
    const float* vp_b  = (const float*)d_in[14];
    const float* op_w  = (const float*)d_in[15];
    const float* op_b  = (const float*)d_in[16];
    const float* n1_w  = (const float*)d_in[17];
    const float* n1_b  = (const float*)d_in[18];
    const float* ff1_w = (const float*)d_in[19];
    const float* ff1_b = (const float*)d_in[20];
    const float* ff2_w = (const float*)d_in[21];
    const float* ff2_b = (const float*)d_in[22];
    const float* n2_w  = (const float*)d_in[23];
    const float* n2_b  = (const float*)d_in[24];
    const float* fn_w  = (const float*)d_in[25];
    const float* fn_b  = (const float*)d_in[26];
    const float* lat_w = (const float*)d_in[27];
    const float* lat_b = (const float*)d_in[28];
    const float* out_w = (const float*)d_in[29];
    const float* gnw   = (const float*)d_in[30];
    const float* gnb   = (const float*)d_in[31];
    float* out = (float*)d_out;

    // ---- workspace (~59 MB; same layout proven safe in rounds 3-5) ----
    float* ws     = (float*)d_ws;
    float* src    = ws;                 // 1376256
    float* pos    = src  + 1376256;     // 1376256 (pong alias after encoder)
    float* tmp    = pos  + 1376256;     // 1376256
    float* valbuf = tmp  + 1376256;     // 1376256 (valb bf16 | latb bf16)
    float* oab    = valbuf + 1376256;   // 1548288
    float* stats  = oab  + 1548288;     // 64
    float* boa    = stats + 64;         // 1728
    float* pong   = pos;                // alias

    unsigned short* valb = (unsigned short*)valbuf;
    unsigned short* latb = (unsigned short*)(valbuf + 688128);

    unsigned short* ub = (unsigned short*)(boa + 1728);
    unsigned short* srcb  = ub; ub += 1376256;
    unsigned short* qbb   = ub; ub += 1376256;  // pingb alias after encoder
    unsigned short* msdb  = ub; ub += 1376256;
    unsigned short* ffhb  = ub; ub += 5505024;  // hosts fT0/1/2 during setup
    unsigned short* w_oa  = ub; ub += 442368;
    unsigned short* w_vp  = ub; ub += 393216;   // contiguous run for cvtall:
    unsigned short* w_op  = ub; ub += 393216;   //   vp|op|ff1|ff2|in0|in1|in2|lat
    unsigned short* w_ff1 = ub; ub += 1572864;
    unsigned short* w_ff2 = ub; ub += 1572864;
    unsigned short* w_in0 = ub; ub += 65536;
    unsigned short* w_in1 = ub; ub += 131072;
    unsigned short* w_in2 = ub; ub += 262144;
    unsigned short* w_lat = ub; ub += 65536;
    unsigned short* wcb   = ub; ub += 1769472;

    unsigned short* fT0 = ffhb;
    unsigned short* fT1 = ffhb + 1048576;
    unsigned short* fT2 = ffhb + 1572864;
    unsigned short* pingb = qbb;

    // ---- setup ----
    pack_oa_k<<<1728, 256, 0, stream>>>(off_w, off_b, aw_w, aw_b, w_oa, boa);
    wconv_k<<<6912, 256, 0, stream>>>(out_w, wcb);
    cvtall_k<<<4352, 256, 0, stream>>>(vp_w, op_w, ff1_w, ff2_w, in0_w, in1_w, in2_w, lat_w, w_vp);
    cvtT_k<<<dim3(128, 8), dim3(32, 8), 0, stream>>>(feat0, fT0, 256, 4096);
    cvtT_k<<<dim3(32, 16), dim3(32, 8), 0, stream>>>(feat1, fT1, 512, 1024);
    cvtT_k<<<dim3(8, 32),  dim3(32, 8), 0, stream>>>(feat2, fT2, 1024, 256);
    posenc_k<<<2688, 256, 0, stream>>>(pos);

    // ---- input projections (fused; also emits qbb = src + pos) ----
    inproj_k<<<dim3(4, 84), 256, 0, stream>>>(fT0, w_in0, in0_b, fT1, w_in1, in1_b,
                                              fT2, w_in2, in2_b, src, srcb, pos, qbb);

    // ---- encoder layers ----
    for (int i = 0; i < 6; i++) {
        oavp_k<<<dim3(9, 84), 256, 0, stream>>>(qbb, w_oa + i*73728, boa + i*288, oab,
                                                srcb, w_vp + i*65536, vp_b + i*256, valb);
        msdef_k<<<672, 256, 0, stream>>>(valb, oab, msdb);
        bgemm_k<<<dim3(4, 84), 256, 0, stream>>>(msdb, w_op + i*65536, op_b + i*256, tmp, nullptr, 256, 256, 0, 0);
        ln_k<true,false><<<1344, 256, 0, stream>>>(src, tmp, n1_w + i*256, n1_b + i*256, srcb, nullptr, nullptr);
        bgemm_k<<<dim3(16, 84), 256, 0, stream>>>(srcb, w_ff1 + i*262144, ff1_b + i*1024, nullptr, ffhb, 1024, 256, 1, 1);
        bgemm_k<<<dim3(4, 84), 256, 0, stream>>>(ffhb, w_ff2 + i*262144, ff2_b + i*256, tmp, nullptr, 256, 1024, 0, 0);
        if (i < 5)
            ln_k<true,true><<<1344, 256, 0, stream>>>(src, tmp, n2_w + i*256, n2_b + i*256, srcb, pos, qbb);
        else
            ln_k<true,false><<<1344, 256, 0, stream>>>(src, tmp, n2_w + i*256, n2_b + i*256, srcb, nullptr, nullptr);
    }
    ln_k<false,false><<<1344, 256, 0, stream>>>(src, nullptr, fn_w, fn_b, srcb, nullptr, nullptr);

    // ---- mems -> d_out (NCHW) ----
    tr_k<<<dim3(128,8), dim3(32,8), 0, stream>>>(src,           out + 1048576, 4096);
    tr_k<<<dim3(32,8),  dim3(32,8), 0, stream>>>(src + 1048576, out + 2097152, 1024);
    tr_k<<<dim3(8,8),   dim3(32,8), 0, stream>>>(src + 1310720, out + 2359296, 256);

    // ---- lateral 1x1 -> bf16 NHWC ----
    bgemm_k<<<dim3(4, 64), 256, 0, stream>>>(srcb, w_lat, lat_b, nullptr, latb, 256, 256, 1, 0);

    // ---- 3x (conv3x3 MFMA -> groupnorm -> relu) ----
    conv3b_k<<<dim3(64,4), 256, 0, stream>>>(latb, wcb, pong);
    gnstats_k<<<32, 256, 0, stream>>>(pong, stats);
    gnapply_b_k<<<1024, 256, 0, stream>>>(pong, stats, gnw, gnb, pingb);

    conv3b_k<<<dim3(64,4), 256, 0, stream>>>(pingb, wcb + 589824, pong);
    gnstats_k<<<32, 256, 0, stream>>>(pong, stats);
    gnapply_b_k<<<1024, 256, 0, stream>>>(pong, stats, gnw + 256, gnb + 256, pingb);

    conv3b_k<<<dim3(64,4), 256, 0, stream>>>(pingb, wcb + 1179648, pong);
    gnstats_k<<<32, 256, 0, stream>>>(pong, stats);
    gnapply_f_k<<<1024, 256, 0, stream>>>(pong, stats, gnw + 512, gnb + 512, out);
}